// Round 11
// baseline (894.104 us; speedup 1.0000x reference)
//
#include <hip/hip_runtime.h>
#include <hip/hip_fp16.h>

#define B_  256
#define T_  512
#define I_  64
#define H_  128
#define G_  384
#define HC  256

// Workspace layout (stream-ordered aliasing: x16 occupies the head of the xw1
// region — gemm overwrites it only after scan_l0 has fully consumed x16).
#define O_OUT0 0ull                    // fp16 [B][T][2H] = 67,108,864
#define O_XW1  67108864ull             // fp16 [B][T][3H] = 100,663,296 (xw1; x16 aliases head)
#define O_X16  O_XW1                   // fp16 [B][T][64] = 16,777,216 (until gemm runs)
#define O_WP   167772160ull            // packed half2 Wih1b, 196,608
#define O_H1F  (O_WP + 196608ull)      // f32 [B][H] = 131,072
#define O_WF16 (O_H1F + 131072ull)     // fp16 Wih1f [384][256] = 196,608

typedef _Float16 h8 __attribute__((ext_vector_type(8)));
typedef _Float16 h2 __attribute__((ext_vector_type(2)));
typedef float    f4 __attribute__((ext_vector_type(4)));

#define MFMA16 __builtin_amdgcn_mfma_f32_16x16x32_f16

__device__ __forceinline__ float sigm(float x)   { return __builtin_amdgcn_rcpf(1.f + __expf(-x)); }
__device__ __forceinline__ float tanh_f(float x) { return 1.f - 2.f * __builtin_amdgcn_rcpf(1.f + __expf(2.f * x)); }

// LDS-only barrier: waits lgkmcnt(0) but NOT vmcnt (prefetch loads/stores stay in flight).
__device__ __forceinline__ void bar_lds() {
    asm volatile("s_waitcnt lgkmcnt(0)\n\ts_barrier" ::: "memory");
}

__device__ __forceinline__ h8 load_w8(const float* src) {
    f4 a = *(const f4*)src;
    f4 b = *(const f4*)(src + 4);
    h8 v;
    v[0]=(_Float16)a[0]; v[1]=(_Float16)a[1]; v[2]=(_Float16)a[2]; v[3]=(_Float16)a[3];
    v[4]=(_Float16)b[0]; v[5]=(_Float16)b[1]; v[6]=(_Float16)b[2]; v[7]=(_Float16)b[3];
    return v;
}

// Fused prep: x->fp16 (4096 blocks), Wih1f->fp16 (48), Wih1b pack-T (192).
__global__ void prep(const float* __restrict__ x, _Float16* __restrict__ x16,
                     const float* __restrict__ Wf, _Float16* __restrict__ wf16,
                     const float* __restrict__ W1b, __half2* __restrict__ wp) {
    const int bid = blockIdx.x;
    const int tid = threadIdx.x;
    if (bid < 4096) {          // x: 1,048,576 groups of 8
        int i = bid * 256 + tid;
        const float* s = x + (size_t)i * 8;
        f4 a = *(const f4*)s, b = *(const f4*)(s + 4);
        h8 v;
        v[0]=(_Float16)a[0]; v[1]=(_Float16)a[1]; v[2]=(_Float16)a[2]; v[3]=(_Float16)a[3];
        v[4]=(_Float16)b[0]; v[5]=(_Float16)b[1]; v[6]=(_Float16)b[2]; v[7]=(_Float16)b[3];
        *(h8*)(x16 + (size_t)i * 8) = v;
    } else if (bid < 4144) {   // Wih1f: 12,288 groups of 8
        int i = (bid - 4096) * 256 + tid;
        const float* s = Wf + (size_t)i * 8;
        f4 a = *(const f4*)s, b = *(const f4*)(s + 4);
        h8 v;
        v[0]=(_Float16)a[0]; v[1]=(_Float16)a[1]; v[2]=(_Float16)a[2]; v[3]=(_Float16)a[3];
        v[4]=(_Float16)b[0]; v[5]=(_Float16)b[1]; v[6]=(_Float16)b[2]; v[7]=(_Float16)b[3];
        *(h8*)(wf16 + (size_t)i * 8) = v;
    } else {                   // Wih1b pack-T: 49,152 items
        int i = (bid - 4144) * 256 + tid;
        int c = i % G_;
        int k2 = i / G_;
        wp[i] = __halves2half2(__float2half(W1b[c * 256 + 2 * k2]),
                               __float2half(W1b[c * 256 + 2 * k2 + 1]));
    }
}

// ---------------- Layer-0 scan: 2 pipelined groups of 4 batches per block ----------------
// Each block owns 8 batches = 2 independent scan streams (G0, G1) sharing weight
// registers. Per step: G0 reads+MFMAs, G1 reads+MFMAs, G0 gates/stores/xpart,
// G1 gates/stores/xpart, ONE barrier. While G0's serial gate chain waits, G1's
// MFMAs and ds_reads fill the pipe — hides ds_read latency + trans chain.
// Within each group: batches at A-rows {0,4,8,12}; valid C = reg 0 of every lane;
// A-frag reads broadcast via row ln15&12 (conflict-free).
__launch_bounds__(512, 1)
__global__ void scan_l0(const _Float16* __restrict__ x16,
                        const float* __restrict__ Wih_f, const float* __restrict__ Whh_f,
                        const float* __restrict__ bih_f, const float* __restrict__ bhh_f,
                        const float* __restrict__ Wih_b, const float* __restrict__ Whh_b,
                        const float* __restrict__ bih_b, const float* __restrict__ bhh_b,
                        _Float16* __restrict__ out0) {
    __shared__ __align__(16) _Float16 s_h[2][2][16 * 128];   // [group][buf]

    const int tid  = threadIdx.x;
    const int lane = tid & 63;
    const int w    = tid >> 6;           // 0..7
    const int dir  = blockIdx.y;
    const int b0   = blockIdx.x * 8;     // 8 batch rows per block (2 groups of 4)

    const float* Wih = dir ? Wih_b : Wih_f;
    const float* Whh = dir ? Whh_b : Whh_f;
    const float* bih = dir ? bih_b : bih_f;
    const float* bhh = dir ? bhh_b : bhh_f;

    for (int i = tid; i < 2 * 2 * 16 * 128; i += 512) ((_Float16*)s_h)[i] = (_Float16)0.f;

    const int ln15 = lane & 15;
    const int lq   = lane >> 4;
    const int col  = 16 * w + ln15;

    h8 bh[3][4], bx[3][2];
    float seedR = bih[col] + bhh[col];
    float seedZ = bih[H_ + col] + bhh[H_ + col];
    float bihN  = bih[2 * H_ + col];
    float bhhN  = bhh[2 * H_ + col];
#pragma unroll
    for (int g = 0; g < 3; g++) {
        int n = g * H_ + col;
#pragma unroll
        for (int kt = 0; kt < 4; kt++) bh[g][kt] = load_w8(Whh + (size_t)n * H_ + kt * 32 + lq * 8);
#pragma unroll
        for (int kt = 0; kt < 2; kt++) bx[g][kt] = load_w8(Wih + (size_t)n * I_ + kt * 32 + lq * 8);
    }
    const int arow = ln15 & 12;          // broadcast A-read row (conflict-free)
    int offh[4];
#pragma unroll
    for (int kt = 0; kt < 4; kt++)
        offh[kt] = arow * 128 + (((kt * 4 + lq) ^ arow) & 15) * 8;
    const int row0  = lq * 4;            // valid C row (reg 0): batch b0+g*4+lq
    const int offw0 = row0 * 128 + ((((col >> 3) ^ row0) & 15)) * 8 + (col & 7);

    const f4 z4 = (f4){0.f, 0.f, 0.f, 0.f};
    const f4 sR4 = (f4){seedR, seedR, seedR, seedR};
    const f4 sZ4 = (f4){seedZ, seedZ, seedZ, seedZ};
    const f4 sXn4 = (f4){bihN, bihN, bihN, bihN};
    const f4 sHn4 = (f4){bhhN, bhhN, bhhN, bhhN};

    const _Float16* xbase[2];
    _Float16* op[2];
    const _Float16* xpA[2];
    const _Float16* xpB[2];
#pragma unroll
    for (int g = 0; g < 2; g++) {
        int bg = b0 + g * 4;
        xbase[g] = x16 + ((size_t)(bg + (ln15 >> 2)) * T_) * I_ + lq * 8;
        op[g] = out0 + ((size_t)(bg + lq) * T_ + (dir ? (T_ - 1) : 0)) * HC + dir * H_ + col;
        xpA[g] = xbase[g] + (size_t)(dir ? (T_ - 4) : 3) * I_;
        xpB[g] = xbase[g] + (size_t)(dir ? (T_ - 5) : 4) * I_;
    }
    const int ostep = dir ? -HC : HC;
    const int xstep = dir ? -(2 * I_) : (2 * I_);

    float hF[2] = {0.f, 0.f};
    float xr0[2], xz0[2], xn0[2], xr1[2], xz1[2], xn1[2];
    h8 xvA0[2], xvA1[2], xvB0[2], xvB1[2];
#pragma unroll
    for (int g = 0; g < 2; g++) {   // prologue per group
        int t0 = dir ? (T_ - 1) : 0;
        int t1 = dir ? (T_ - 2) : 1;
        int t2 = dir ? (T_ - 3) : 2;
        h8 xc0 = *(const h8*)(xbase[g] + (size_t)t0 * I_);
        h8 xc1 = *(const h8*)(xbase[g] + (size_t)t0 * I_ + 32);
        xvA0[g] = *(const h8*)(xbase[g] + (size_t)t1 * I_);
        xvA1[g] = *(const h8*)(xbase[g] + (size_t)t1 * I_ + 32);
        xvB0[g] = *(const h8*)(xbase[g] + (size_t)t2 * I_);
        xvB1[g] = *(const h8*)(xbase[g] + (size_t)t2 * I_ + 32);
        f4 aXr = sR4, aXz = sZ4, aXn = sXn4;
        aXr = MFMA16(xc0, bx[0][0], aXr, 0, 0, 0);
        aXz = MFMA16(xc0, bx[1][0], aXz, 0, 0, 0);
        aXn = MFMA16(xc0, bx[2][0], aXn, 0, 0, 0);
        aXr = MFMA16(xc1, bx[0][1], aXr, 0, 0, 0);
        aXz = MFMA16(xc1, bx[1][1], aXz, 0, 0, 0);
        aXn = MFMA16(xc1, bx[2][1], aXn, 0, 0, 0);
        xr0[g] = aXr[0]; xz0[g] = aXz[0]; xn0[g] = aXn[0];
    }
    __syncthreads();

#pragma unroll 1
    for (int t = 0; t < T_; t += 2) {
        {   // even step s=t: read s_h[g][0] -> write s_h[g][1], consume set0
            h8 ah[2][4];
            f4 hRa[2], hRb[2], hZa[2], hZb[2], hNa[2], hNb[2];
#pragma unroll
            for (int g = 0; g < 2; g++) {
#pragma unroll
                for (int kt = 0; kt < 4; kt++) ah[g][kt] = *(const h8*)&s_h[g][0][offh[kt]];
                hRa[g] = z4; hRb[g] = z4; hZa[g] = z4; hZb[g] = z4; hNa[g] = sHn4; hNb[g] = z4;
                hRa[g] = MFMA16(ah[g][0], bh[0][0], hRa[g], 0, 0, 0);
                hZa[g] = MFMA16(ah[g][0], bh[1][0], hZa[g], 0, 0, 0);
                hNa[g] = MFMA16(ah[g][0], bh[2][0], hNa[g], 0, 0, 0);
                hRb[g] = MFMA16(ah[g][2], bh[0][2], hRb[g], 0, 0, 0);
                hZb[g] = MFMA16(ah[g][2], bh[1][2], hZb[g], 0, 0, 0);
                hNb[g] = MFMA16(ah[g][2], bh[2][2], hNb[g], 0, 0, 0);
                hRa[g] = MFMA16(ah[g][1], bh[0][1], hRa[g], 0, 0, 0);
                hZa[g] = MFMA16(ah[g][1], bh[1][1], hZa[g], 0, 0, 0);
                hNa[g] = MFMA16(ah[g][1], bh[2][1], hNa[g], 0, 0, 0);
                hRb[g] = MFMA16(ah[g][3], bh[0][3], hRb[g], 0, 0, 0);
                hZb[g] = MFMA16(ah[g][3], bh[1][3], hZb[g], 0, 0, 0);
                hNb[g] = MFMA16(ah[g][3], bh[2][3], hNb[g], 0, 0, 0);
            }
#pragma unroll
            for (int g = 0; g < 2; g++) {
                float r = sigm(xr0[g] + hRa[g][0] + hRb[g][0]);
                float z = sigm(xz0[g] + hZa[g][0] + hZb[g][0]);
                float n = tanh_f(xn0[g] + r * (hNa[g][0] + hNb[g][0]));
                float h = n + z * (hF[g] - n);
                hF[g] = h;
                s_h[g][1][offw0] = (_Float16)h;
                *op[g] = (_Float16)h; op[g] += ostep;
                {   // xpart set1 from xvA (off critical path)
                    f4 aXr = sR4, aXz = sZ4, aXn = sXn4;
                    aXr = MFMA16(xvA0[g], bx[0][0], aXr, 0, 0, 0);
                    aXz = MFMA16(xvA0[g], bx[1][0], aXz, 0, 0, 0);
                    aXn = MFMA16(xvA0[g], bx[2][0], aXn, 0, 0, 0);
                    aXr = MFMA16(xvA1[g], bx[0][1], aXr, 0, 0, 0);
                    aXz = MFMA16(xvA1[g], bx[1][1], aXz, 0, 0, 0);
                    aXn = MFMA16(xvA1[g], bx[2][1], aXn, 0, 0, 0);
                    xr1[g] = aXr[0]; xz1[g] = aXz[0]; xn1[g] = aXn[0];
                }
                if (t + 3 < T_) {   // reload xvA <- x(t+3)
                    xvA0[g] = *(const h8*)(xpA[g]);
                    xvA1[g] = *(const h8*)(xpA[g] + 32);
                    xpA[g] += xstep;
                }
            }
            bar_lds();
        }
        {   // odd step s=t+1: read s_h[g][1] -> write s_h[g][0], consume set1
            h8 ah[2][4];
            f4 hRa[2], hRb[2], hZa[2], hZb[2], hNa[2], hNb[2];
#pragma unroll
            for (int g = 0; g < 2; g++) {
#pragma unroll
                for (int kt = 0; kt < 4; kt++) ah[g][kt] = *(const h8*)&s_h[g][1][offh[kt]];
                hRa[g] = z4; hRb[g] = z4; hZa[g] = z4; hZb[g] = z4; hNa[g] = sHn4; hNb[g] = z4;
                hRa[g] = MFMA16(ah[g][0], bh[0][0], hRa[g], 0, 0, 0);
                hZa[g] = MFMA16(ah[g][0], bh[1][0], hZa[g], 0, 0, 0);
                hNa[g] = MFMA16(ah[g][0], bh[2][0], hNa[g], 0, 0, 0);
                hRb[g] = MFMA16(ah[g][2], bh[0][2], hRb[g], 0, 0, 0);
                hZb[g] = MFMA16(ah[g][2], bh[1][2], hZb[g], 0, 0, 0);
                hNb[g] = MFMA16(ah[g][2], bh[2][2], hNb[g], 0, 0, 0);
                hRa[g] = MFMA16(ah[g][1], bh[0][1], hRa[g], 0, 0, 0);
                hZa[g] = MFMA16(ah[g][1], bh[1][1], hZa[g], 0, 0, 0);
                hNa[g] = MFMA16(ah[g][1], bh[2][1], hNa[g], 0, 0, 0);
                hRb[g] = MFMA16(ah[g][3], bh[0][3], hRb[g], 0, 0, 0);
                hZb[g] = MFMA16(ah[g][3], bh[1][3], hZb[g], 0, 0, 0);
                hNb[g] = MFMA16(ah[g][3], bh[2][3], hNb[g], 0, 0, 0);
            }
#pragma unroll
            for (int g = 0; g < 2; g++) {
                float r = sigm(xr1[g] + hRa[g][0] + hRb[g][0]);
                float z = sigm(xz1[g] + hZa[g][0] + hZb[g][0]);
                float n = tanh_f(xn1[g] + r * (hNa[g][0] + hNb[g][0]));
                float h = n + z * (hF[g] - n);
                hF[g] = h;
                s_h[g][0][offw0] = (_Float16)h;
                *op[g] = (_Float16)h; op[g] += ostep;
                if (t + 2 < T_) {   // xpart set0 from xvB
                    f4 aXr = sR4, aXz = sZ4, aXn = sXn4;
                    aXr = MFMA16(xvB0[g], bx[0][0], aXr, 0, 0, 0);
                    aXz = MFMA16(xvB0[g], bx[1][0], aXz, 0, 0, 0);
                    aXn = MFMA16(xvB0[g], bx[2][0], aXn, 0, 0, 0);
                    aXr = MFMA16(xvB1[g], bx[0][1], aXr, 0, 0, 0);
                    aXz = MFMA16(xvB1[g], bx[1][1], aXz, 0, 0, 0);
                    aXn = MFMA16(xvB1[g], bx[2][1], aXn, 0, 0, 0);
                    xr0[g] = aXr[0]; xz0[g] = aXz[0]; xn0[g] = aXn[0];
                }
                if (t + 4 < T_) {   // reload xvB <- x(t+4)
                    xvB0[g] = *(const h8*)(xpB[g]);
                    xvB1[g] = *(const h8*)(xpB[g] + 32);
                    xpB[g] += xstep;
                }
            }
            bar_lds();
        }
    }
}

// ---------------- MFMA GEMM v4: per-block M=64, full N=384 (unchanged) ----------------
// Output rows gate-permuted: n<256 -> (n&127)*2+(n>>7); n>=256 -> n.
__launch_bounds__(256, 1)
__global__ void gemm_xw1(const _Float16* __restrict__ A,   // [M][256]
                         const _Float16* __restrict__ Bw,  // [384][256] fp16
                         const float* __restrict__ bias,
                         _Float16* __restrict__ C) {       // [M][384] permuted rows
    __shared__ __align__(16) _Float16 sA[2][64 * 64];
    __shared__ __align__(16) _Float16 sB[2][384 * 64];
    const int tid  = threadIdx.x;
    const int lane = tid & 63;
    const int w    = tid >> 6;
    const int wm   = w & 1, wn = w >> 1;      // M-half (32 rows), N-half (192 cols)
    const int ln15 = lane & 15, lq = lane >> 4;
    const size_t m0 = (size_t)blockIdx.x * 64;

    f4 acc[2][12] = {};

    int aRow[2], aG[2], aOff[2];
#pragma unroll
    for (int k = 0; k < 2; k++) {
        int idx = k * 256 + tid;               // 512 granules: 64 rows x 8
        aRow[k] = idx >> 3; aG[k] = idx & 7;
        aOff[k] = aRow[k] * 64 + ((aG[k] ^ (aRow[k] & 7)) & 7) * 8;
    }
    int bRow[12], bG[12], bOff[12];
#pragma unroll
    for (int k = 0; k < 12; k++) {
        int idx = k * 256 + tid;               // 3072 granules: 384 rows x 8
        bRow[k] = idx >> 3; bG[k] = idx & 7;
        bOff[k] = bRow[k] * 64 + ((bG[k] ^ (bRow[k] & 7)) & 7) * 8;
    }
    int offA[2][2], offB[12][2];
#pragma unroll
    for (int mt = 0; mt < 2; mt++)
#pragma unroll
        for (int kt = 0; kt < 2; kt++) {
            int row = wm * 32 + mt * 16 + ln15;
            offA[mt][kt] = row * 64 + (((kt * 4 + lq) ^ (row & 7)) & 7) * 8;
        }
#pragma unroll
    for (int nt = 0; nt < 12; nt++)
#pragma unroll
        for (int kt = 0; kt < 2; kt++) {
            int row = wn * 192 + nt * 16 + ln15;
            offB[nt][kt] = row * 64 + (((kt * 4 + lq) ^ (row & 7)) & 7) * 8;
        }

    {   // prologue: chunk 0 -> buf 0
        h8 av[2], bv[12];
#pragma unroll
        for (int k = 0; k < 2; k++) av[k] = *(const h8*)(A + (m0 + aRow[k]) * 256 + aG[k] * 8);
#pragma unroll
        for (int k = 0; k < 12; k++) bv[k] = *(const h8*)(Bw + (size_t)bRow[k] * 256 + bG[k] * 8);
#pragma unroll
        for (int k = 0; k < 2; k++) *(h8*)&sA[0][aOff[k]] = av[k];
#pragma unroll
        for (int k = 0; k < 12; k++) *(h8*)&sB[0][bOff[k]] = bv[k];
        bar_lds();
    }

#pragma unroll
    for (int c = 0; c < 4; c++) {
        const int cur = c & 1;
        h8 av[2], bv[12];
        if (c < 3) {   // prefetch chunk c+1 (latency hidden under 48 MFMAs)
#pragma unroll
            for (int k = 0; k < 2; k++)
                av[k] = *(const h8*)(A + (m0 + aRow[k]) * 256 + (c + 1) * 64 + aG[k] * 8);
#pragma unroll
            for (int k = 0; k < 12; k++)
                bv[k] = *(const h8*)(Bw + (size_t)bRow[k] * 256 + (c + 1) * 64 + bG[k] * 8);
        }
#pragma unroll
        for (int kt = 0; kt < 2; kt++) {
            h8 af0 = *(const h8*)&sA[cur][offA[0][kt]];
            h8 af1 = *(const h8*)&sA[cur][offA[1][kt]];
#pragma unroll
            for (int nt = 0; nt < 12; nt++) {
                h8 bf = *(const h8*)&sB[cur][offB[nt][kt]];
                acc[0][nt] = MFMA16(af0, bf, acc[0][nt], 0, 0, 0);
                acc[1][nt] = MFMA16(af1, bf, acc[1][nt], 0, 0, 0);
            }
        }
        if (c < 3) {
#pragma unroll
            for (int k = 0; k < 2; k++) *(h8*)&sA[cur ^ 1][aOff[k]] = av[k];
#pragma unroll
            for (int k = 0; k < 12; k++) *(h8*)&sB[cur ^ 1][bOff[k]] = bv[k];
            bar_lds();
        }
    }
#pragma unroll
    for (int nt = 0; nt < 12; nt++) {
        int col = wn * 192 + nt * 16 + ln15;
        float bb = bias[col];
        int pcol = (col < 256) ? ((col & 127) * 2 + (col >> 7)) : col;
#pragma unroll
        for (int mt = 0; mt < 2; mt++) {
            size_t row = m0 + wm * 32 + mt * 16 + lq * 4;
#pragma unroll
            for (int reg = 0; reg < 4; reg++)
                C[(row + reg) * G_ + pcol] = (_Float16)(acc[mt][nt][reg] + bb);
        }
    }
}

// ---------------- Layer-1 fwd scan: 2 pipelined groups of 4 batches per block ----------------
// Same pairing as scan_l0; gates register-prefetched from xw1 via running
// pointers (2 steps ahead), no LDS ring.
__launch_bounds__(512, 1)
__global__ void scan_l1(const _Float16* __restrict__ xw1,
                        const float* __restrict__ Whh,
                        const float* __restrict__ bhh,
                        float* __restrict__ h1f) {
    __shared__ __align__(16) _Float16 s_h[2][2][16 * 128];

    const int tid  = threadIdx.x;
    const int lane = tid & 63;
    const int w    = tid >> 6;
    const int b0   = blockIdx.x * 8;

    for (int i = tid; i < 2 * 2 * 16 * 128; i += 512) ((_Float16*)s_h)[i] = (_Float16)0.f;

    const int ln15 = lane & 15;
    const int lq   = lane >> 4;
    const int col  = 16 * w + ln15;

    h8 bh[3][4];
    float bhhF[3];
#pragma unroll
    for (int g = 0; g < 3; g++) {
        int n = g * H_ + col;
        bhhF[g] = bhh[n];
#pragma unroll
        for (int kt = 0; kt < 4; kt++) bh[g][kt] = load_w8(Whh + (size_t)n * H_ + kt * 32 + lq * 8);
    }
    const int arow = ln15 & 12;
    int offh[4];
#pragma unroll
    for (int kt = 0; kt < 4; kt++)
        offh[kt] = arow * 128 + (((kt * 4 + lq) ^ arow) & 15) * 8;
    const int row0  = lq * 4;
    const int offw0 = row0 * 128 + ((((col >> 3) ^ row0) & 15)) * 8 + (col & 7);

    const f4 z4 = (f4){0.f, 0.f, 0.f, 0.f};
    const f4 sR4 = (f4){bhhF[0], bhhF[0], bhhF[0], bhhF[0]};
    const f4 sZ4 = (f4){bhhF[1], bhhF[1], bhhF[1], bhhF[1]};
    const f4 sN4 = (f4){bhhF[2], bhhF[2], bhhF[2], bhhF[2]};

    const _Float16* rzbase[2];
    const _Float16* nbase[2];
#pragma unroll
    for (int g = 0; g < 2; g++) {
        int bg = b0 + g * 4;
        rzbase[g] = xw1 + ((size_t)(bg + lq) * T_) * G_ + 2 * col;
        nbase[g]  = xw1 + ((size_t)(bg + lq) * T_) * G_ + 256 + col;
    }

    __syncthreads();

    float hF[2] = {0.f, 0.f};
    h2 rzA[2], rzB[2];
    _Float16 nA[2], nB[2];
    const _Float16* rzP2[2];
    const _Float16* nP2[2];
    const _Float16* rzP3[2];
    const _Float16* nP3[2];
#pragma unroll
    for (int g = 0; g < 2; g++) {
        rzA[g] = *(const h2*)(rzbase[g]);
        rzB[g] = *(const h2*)(rzbase[g] + G_);
        nA[g] = *nbase[g];
        nB[g] = *(nbase[g] + G_);
        rzP2[g] = rzbase[g] + 2 * G_;
        nP2[g]  = nbase[g]  + 2 * G_;
        rzP3[g] = rzbase[g] + 3 * G_;
        nP3[g]  = nbase[g]  + 3 * G_;
    }

#pragma unroll 1
    for (int s = 0; s < T_; s += 2) {
        {   // even step: read s_h[g][0] -> write s_h[g][1]
            h8 ah[2][4];
            f4 hRa[2], hRb[2], hZa[2], hZb[2], hNa[2], hNb[2];
            float xr[2], xz[2], xn[2];
#pragma unroll
            for (int g = 0; g < 2; g++) {
#pragma unroll
                for (int kt = 0; kt < 4; kt++) ah[g][kt] = *(const h8*)&s_h[g][0][offh[kt]];
                xr[g] = (float)rzA[g][0]; xz[g] = (float)rzA[g][1]; xn[g] = (float)nA[g];
                if (s + 2 < T_) {
                    rzA[g] = *(const h2*)rzP2[g];
                    nA[g]  = *nP2[g];
                    rzP2[g] += 2 * G_; nP2[g] += 2 * G_;
                }
                hRa[g] = sR4; hRb[g] = z4; hZa[g] = sZ4; hZb[g] = z4; hNa[g] = sN4; hNb[g] = z4;
                hRa[g] = MFMA16(ah[g][0], bh[0][0], hRa[g], 0, 0, 0);
                hZa[g] = MFMA16(ah[g][0], bh[1][0], hZa[g], 0, 0, 0);
                hNa[g] = MFMA16(ah[g][0], bh[2][0], hNa[g], 0, 0, 0);
                hRb[g] = MFMA16(ah[g][2], bh[0][2], hRb[g], 0, 0, 0);
                hZb[g] = MFMA16(ah[g][2], bh[1][2], hZb[g], 0, 0, 0);
                hNb[g] = MFMA16(ah[g][2], bh[2][2], hNb[g], 0, 0, 0);
                hRa[g] = MFMA16(ah[g][1], bh[0][1], hRa[g], 0, 0, 0);
                hZa[g] = MFMA16(ah[g][1], bh[1][1], hZa[g], 0, 0, 0);
                hNa[g] = MFMA16(ah[g][1], bh[2][1], hNa[g], 0, 0, 0);
                hRb[g] = MFMA16(ah[g][3], bh[0][3], hRb[g], 0, 0, 0);
                hZb[g] = MFMA16(ah[g][3], bh[1][3], hZb[g], 0, 0, 0);
                hNb[g] = MFMA16(ah[g][3], bh[2][3], hNb[g], 0, 0, 0);
            }
#pragma unroll
            for (int g = 0; g < 2; g++) {
                float r = sigm(xr[g] + hRa[g][0] + hRb[g][0]);
                float z = sigm(xz[g] + hZa[g][0] + hZb[g][0]);
                float n = tanh_f(xn[g] + r * (hNa[g][0] + hNb[g][0]));
                float h = n + z * (hF[g] - n);
                hF[g] = h;
                s_h[g][1][offw0] = (_Float16)h;
            }
            bar_lds();
        }
        {   // odd step: read s_h[g][1] -> write s_h[g][0]
            h8 ah[2][4];
            f4 hRa[2], hRb[2], hZa[2], hZb[2], hNa[2], hNb[2];
            float xr[2], xz[2], xn[2];
#pragma unroll
            for (int g = 0; g < 2; g++) {
#pragma unroll
                for (int kt = 0; kt < 4; kt++) ah[g][kt] = *(const h8*)&s_h[g][1][offh[kt]];
                xr[g] = (float)rzB[g][0]; xz[g] = (float)rzB[g][1]; xn[g] = (float)nB[g];
                if (s + 3 < T_) {
                    rzB[g] = *(const h2*)rzP3[g];
                    nB[g]  = *nP3[g];
                    rzP3[g] += 2 * G_; nP3[g] += 2 * G_;
                }
                hRa[g] = sR4; hRb[g] = z4; hZa[g] = sZ4; hZb[g] = z4; hNa[g] = sN4; hNb[g] = z4;
                hRa[g] = MFMA16(ah[g][0], bh[0][0], hRa[g], 0, 0, 0);
                hZa[g] = MFMA16(ah[g][0], bh[1][0], hZa[g], 0, 0, 0);
                hNa[g] = MFMA16(ah[g][0], bh[2][0], hNa[g], 0, 0, 0);
                hRb[g] = MFMA16(ah[g][2], bh[0][2], hRb[g], 0, 0, 0);
                hZb[g] = MFMA16(ah[g][2], bh[1][2], hZb[g], 0, 0, 0);
                hNb[g] = MFMA16(ah[g][2], bh[2][2], hNb[g], 0, 0, 0);
                hRa[g] = MFMA16(ah[g][1], bh[0][1], hRa[g], 0, 0, 0);
                hZa[g] = MFMA16(ah[g][1], bh[1][1], hZa[g], 0, 0, 0);
                hNa[g] = MFMA16(ah[g][1], bh[2][1], hNa[g], 0, 0, 0);
                hRb[g] = MFMA16(ah[g][3], bh[0][3], hRb[g], 0, 0, 0);
                hZb[g] = MFMA16(ah[g][3], bh[1][3], hZb[g], 0, 0, 0);
                hNb[g] = MFMA16(ah[g][3], bh[2][3], hNb[g], 0, 0, 0);
            }
#pragma unroll
            for (int g = 0; g < 2; g++) {
                float r = sigm(xr[g] + hRa[g][0] + hRb[g][0]);
                float z = sigm(xz[g] + hZa[g][0] + hZb[g][0]);
                float n = tanh_f(xn[g] + r * (hNa[g][0] + hNb[g][0]));
                float h = n + z * (hF[g] - n);
                hF[g] = h;
                s_h[g][0][offw0] = (_Float16)h;
            }
            bar_lds();
        }
    }
#pragma unroll
    for (int g = 0; g < 2; g++)
        h1f[(size_t)(b0 + g * 4 + lq) * H_ + col] = hF[g];
}

// ---------------- Tail: layer-1 bwd single step + relu + FC (unchanged) ----------------
__launch_bounds__(384)
__global__ void final_k(const _Float16* __restrict__ out0,
                        const float* __restrict__ h1f,
                        const __half2* __restrict__ w1b,
                        const float* __restrict__ bih1b, const float* __restrict__ bhh1b,
                        const float* __restrict__ fcw, const float* __restrict__ fcb,
                        float* __restrict__ out) {
    __shared__ __align__(16) float s_x1[HC];
    __shared__ __align__(16) float s_xw[G_];
    __shared__ __align__(16) float s_hc[HC];
    __shared__ float s_red[8];
    const int tid = threadIdx.x;
    const int b = blockIdx.x;
    if (tid < HC)
        s_x1[tid] = (float)out0[((size_t)b * T_ + (T_ - 1)) * HC + tid];
    __syncthreads();
    {
        float acc0 = 0.f, acc1 = 0.f;
        const float2* xv = (const float2*)s_x1;
#pragma unroll 8
        for (int k2 = 0; k2 < 128; k2 += 2) {
            float2 w0 = __half22float2(w1b[k2 * G_ + tid]);
            float2 w1 = __half22float2(w1b[(k2 + 1) * G_ + tid]);
            float2 a0 = xv[k2], a1 = xv[k2 + 1];
            acc0 += a0.x * w0.x + a0.y * w0.y;
            acc1 += a1.x * w1.x + a1.y * w1.y;
        }
        s_xw[tid] = bih1b[tid] + acc0 + acc1;
    }
    __syncthreads();
    if (tid < H_) {
        int j = tid;
        float rg = sigm(s_xw[j] + bhh1b[j]);
        float zg = sigm(s_xw[H_ + j] + bhh1b[H_ + j]);
        float ng = tanh_f(s_xw[2 * H_ + j] + rg * bhh1b[2 * H_ + j]);
        float hb = (1.f - zg) * ng;
        s_hc[H_ + j] = fmaxf(hb, 0.f);
        s_hc[j] = fmaxf(h1f[(size_t)b * H_ + j], 0.f);
    }
    __syncthreads();
    if (tid < HC) {
        float hv = s_hc[tid];
        float p0 = hv * fcw[tid];
        float p1 = hv * fcw[HC + tid];
#pragma unroll
        for (int off = 32; off; off >>= 1) {
            p0 += __shfl_down(p0, off);
            p1 += __shfl_down(p1, off);
        }
        if ((tid & 63) == 0) { s_red[(tid >> 6) * 2] = p0; s_red[(tid >> 6) * 2 + 1] = p1; }
    }
    __syncthreads();
    if (tid == 0) {
        out[b * 2 + 0] = fcb[0] + s_red[0] + s_red[2] + s_red[4] + s_red[6];
        out[b * 2 + 1] = fcb[1] + s_red[1] + s_red[3] + s_red[5] + s_red[7];
    }
}

extern "C" void kernel_launch(void* const* d_in, const int* in_sizes, int n_in,
                              void* d_out, int out_size, void* d_ws, size_t ws_size,
                              hipStream_t stream) {
    (void)in_sizes; (void)n_in; (void)out_size; (void)ws_size;
    const float* x     = (const float*)d_in[0];
    const float* Wih0f = (const float*)d_in[1];
    const float* Whh0f = (const float*)d_in[2];
    const float* bih0f = (const float*)d_in[3];
    const float* bhh0f = (const float*)d_in[4];
    const float* Wih0b = (const float*)d_in[5];
    const float* Whh0b = (const float*)d_in[6];
    const float* bih0b = (const float*)d_in[7];
    const float* bhh0b = (const float*)d_in[8];
    const float* Wih1f = (const float*)d_in[9];
    const float* Whh1f = (const float*)d_in[10];
    const float* bih1f = (const float*)d_in[11];
    const float* bhh1f = (const float*)d_in[12];
    const float* Wih1b = (const float*)d_in[13];
    const float* bih1b = (const float*)d_in[15];
    const float* bhh1b = (const float*)d_in[16];
    const float* fcw   = (const float*)d_in[17];
    const float* fcb   = (const float*)d_in[18];

    char* ws = (char*)d_ws;
    _Float16* out0 = (_Float16*)(ws + O_OUT0);
    _Float16* xw1  = (_Float16*)(ws + O_XW1);
    _Float16* x16  = (_Float16*)(ws + O_X16);
    __half2*  wp   = (__half2*)(ws + O_WP);
    float*    h1f  = (float*)(ws + O_H1F);
    _Float16* wf16 = (_Float16*)(ws + O_WF16);
    float*    out  = (float*)d_out;

    prep<<<4336, 256, 0, stream>>>(x, x16, Wih1f, wf16, Wih1b, wp);

    scan_l0<<<dim3(32, 2), 512, 0, stream>>>(x16, Wih0f, Whh0f, bih0f, bhh0f,
                                             Wih0b, Whh0b, bih0b, bhh0b, out0);

    gemm_xw1<<<2048, 256, 0, stream>>>(out0, wf16, bih1f, xw1);

    scan_l1<<<32, 512, 0, stream>>>(xw1, Whh1f, bhh1f, h1f);

    final_k<<<256, 384, 0, stream>>>(out0, h1f, wp, bih1b, bhh1b, fcw, fcb, out);
}

// Round 12
// 641.656 us; speedup vs baseline: 1.3934x; 1.3934x over previous
//
#include <hip/hip_runtime.h>
#include <hip/hip_fp16.h>

#define B_  256
#define T_  512
#define I_  64
#define H_  128
#define G_  384
#define HC  256

#define O_OUT0 0ull
#define O_XW1  67108864ull
#define O_X16  O_XW1
#define O_WP   167772160ull
#define O_H1F  (O_WP + 196608ull)
#define O_WF16 (O_H1F + 131072ull)

typedef _Float16 h8 __attribute__((ext_vector_type(8)));
typedef _Float16 h2 __attribute__((ext_vector_type(2)));
typedef float    f4 __attribute__((ext_vector_type(4)));

#define MFMA16 __builtin_amdgcn_mfma_f32_16x16x32_f16

__device__ __forceinline__ float sigm(float x)   { return __builtin_amdgcn_rcpf(1.f + __expf(-x)); }
__device__ __forceinline__ float tanh_f(float x) { return 1.f - 2.f * __builtin_amdgcn_rcpf(1.f + __expf(2.f * x)); }

__device__ __forceinline__ void bar_lds() {
    asm volatile("s_waitcnt lgkmcnt(0)\n\ts_barrier" ::: "memory");
}

__device__ __forceinline__ h8 load_w8(const float* src) {
    f4 a = *(const f4*)src;
    f4 b = *(const f4*)(src + 4);
    h8 v;
    v[0]=(_Float16)a[0]; v[1]=(_Float16)a[1]; v[2]=(_Float16)a[2]; v[3]=(_Float16)a[3];
    v[4]=(_Float16)b[0]; v[5]=(_Float16)b[1]; v[6]=(_Float16)b[2]; v[7]=(_Float16)b[3];
    return v;
}

// Fused prep: x->fp16 (4096 blocks), Wih1f->fp16 (48), Wih1b pack-T (192).
__global__ void prep(const float* __restrict__ x, _Float16* __restrict__ x16,
                     const float* __restrict__ Wf, _Float16* __restrict__ wf16,
                     const float* __restrict__ W1b, __half2* __restrict__ wp) {
    const int bid = blockIdx.x;
    const int tid = threadIdx.x;
    if (bid < 4096) {
        int i = bid * 256 + tid;
        const float* s = x + (size_t)i * 8;
        f4 a = *(const f4*)s, b = *(const f4*)(s + 4);
        h8 v;
        v[0]=(_Float16)a[0]; v[1]=(_Float16)a[1]; v[2]=(_Float16)a[2]; v[3]=(_Float16)a[3];
        v[4]=(_Float16)b[0]; v[5]=(_Float16)b[1]; v[6]=(_Float16)b[2]; v[7]=(_Float16)b[3];
        *(h8*)(x16 + (size_t)i * 8) = v;
    } else if (bid < 4144) {
        int i = (bid - 4096) * 256 + tid;
        const float* s = Wf + (size_t)i * 8;
        f4 a = *(const f4*)s, b = *(const f4*)(s + 4);
        h8 v;
        v[0]=(_Float16)a[0]; v[1]=(_Float16)a[1]; v[2]=(_Float16)a[2]; v[3]=(_Float16)a[3];
        v[4]=(_Float16)b[0]; v[5]=(_Float16)b[1]; v[6]=(_Float16)b[2]; v[7]=(_Float16)b[3];
        *(h8*)(wf16 + (size_t)i * 8) = v;
    } else {
        int i = (bid - 4144) * 256 + tid;
        int c = i % G_;
        int k2 = i / G_;
        wp[i] = __halves2half2(__float2half(W1b[c * 256 + 2 * k2]),
                               __float2half(W1b[c * 256 + 2 * k2 + 1]));
    }
}

// ---------------- Layer-0 scan: 4 rows/block + 2-timestep-packed x-MFMAs ----------------
// Batches at A-rows {0,4,8,12}; valid h C-data = reg 0 of every lane.
// x-part packing: A-row r -> batch (r>>2), time-slot bit (r>>1)&1. One 6-MFMA set
// yields gates for TWO steps: reg0 (bit=0, step sA) and reg2 (bit=1, step sA+1).
// Per 2-step iter: 6 x-MFMAs (was 12), 2 packed h8 loads (was 4).
// A-frag h reads broadcast via row ln15&12 (conflict-free). Flat MFMA chains.
__launch_bounds__(512, 1)
__global__ void scan_l0(const _Float16* __restrict__ x16,
                        const float* __restrict__ Wih_f, const float* __restrict__ Whh_f,
                        const float* __restrict__ bih_f, const float* __restrict__ bhh_f,
                        const float* __restrict__ Wih_b, const float* __restrict__ Whh_b,
                        const float* __restrict__ bih_b, const float* __restrict__ bhh_b,
                        _Float16* __restrict__ out0) {
    __shared__ __align__(16) _Float16 s_h[2][16 * 128];

    const int tid  = threadIdx.x;
    const int lane = tid & 63;
    const int w    = tid >> 6;           // 0..7
    const int dir  = blockIdx.y;
    const int b0   = blockIdx.x * 4;

    const float* Wih = dir ? Wih_b : Wih_f;
    const float* Whh = dir ? Whh_b : Whh_f;
    const float* bih = dir ? bih_b : bih_f;
    const float* bhh = dir ? bhh_b : bhh_f;

    for (int i = tid; i < 2 * 16 * 128; i += 512) ((_Float16*)s_h)[i] = (_Float16)0.f;

    const int ln15 = lane & 15;
    const int lq   = lane >> 4;
    const int col  = 16 * w + ln15;

    h8 bh[3][4], bx[3][2];
    float seedR = bih[col] + bhh[col];
    float seedZ = bih[H_ + col] + bhh[H_ + col];
    float bihN  = bih[2 * H_ + col];
    float bhhN  = bhh[2 * H_ + col];
#pragma unroll
    for (int g = 0; g < 3; g++) {
        int n = g * H_ + col;
#pragma unroll
        for (int kt = 0; kt < 4; kt++) bh[g][kt] = load_w8(Whh + (size_t)n * H_ + kt * 32 + lq * 8);
#pragma unroll
        for (int kt = 0; kt < 2; kt++) bx[g][kt] = load_w8(Wih + (size_t)n * I_ + kt * 32 + lq * 8);
    }
    const int arow = ln15 & 12;          // broadcast A-read row (conflict-free)
    int offh[4];
#pragma unroll
    for (int kt = 0; kt < 4; kt++)
        offh[kt] = arow * 128 + (((kt * 4 + lq) ^ arow) & 15) * 8;
    const int row0  = lq * 4;
    const int offw0 = row0 * 128 + ((((col >> 3) ^ row0) & 15)) * 8 + (col & 7);

    const f4 z4 = (f4){0.f, 0.f, 0.f, 0.f};
    const f4 sR4 = (f4){seedR, seedR, seedR, seedR};
    const f4 sZ4 = (f4){seedZ, seedZ, seedZ, seedZ};
    const f4 sXn4 = (f4){bihN, bihN, bihN, bihN};
    const f4 sHn4 = (f4){bhhN, bhhN, bhhN, bhhN};

    // x packed-lane pointer: batch = b0 + (ln15>>2); time bit = (ln15>>1)&1.
    const int tbit = (ln15 >> 1) & 1;
    const _Float16* xpb = x16 + ((size_t)(b0 + (ln15 >> 2)) * T_ + (dir ? (T_ - 1 - tbit) : tbit)) * I_ + lq * 8;
    const int xIterStep = dir ? -(2 * I_) : (2 * I_);   // advance 2 timesteps per iter

    _Float16* op = out0 + ((size_t)(b0 + lq) * T_ + (dir ? (T_ - 1) : 0)) * HC + dir * H_ + col;
    const int ostep = dir ? -HC : HC;

    float hF = 0.f;
    float xrA, xzA, xnA, xrB, xzB, xnB;        // gates for current even/odd step
    float nxrA, nxzA, nxnA, nxrB, nxzB, nxnB;  // next pair (computed during even step)
    h8 xv0, xv1;                               // packed x for steps (t+2, t+3)
    {   // prologue: gates(0,1) from packed x(0,1); issue xv <- x(2,3)
        h8 xc0 = *(const h8*)(xpb);
        h8 xc1 = *(const h8*)(xpb + 32);
        xv0 = *(const h8*)(xpb + xIterStep);
        xv1 = *(const h8*)(xpb + xIterStep + 32);
        f4 aXr = sR4, aXz = sZ4, aXn = sXn4;
        aXr = MFMA16(xc0, bx[0][0], aXr, 0, 0, 0);
        aXz = MFMA16(xc0, bx[1][0], aXz, 0, 0, 0);
        aXn = MFMA16(xc0, bx[2][0], aXn, 0, 0, 0);
        aXr = MFMA16(xc1, bx[0][1], aXr, 0, 0, 0);
        aXz = MFMA16(xc1, bx[1][1], aXz, 0, 0, 0);
        aXn = MFMA16(xc1, bx[2][1], aXn, 0, 0, 0);
        xrA = aXr[0]; xzA = aXz[0]; xnA = aXn[0];   // step 0 (reg0, bit=0)
        xrB = aXr[2]; xzB = aXz[2]; xnB = aXn[2];   // step 1 (reg2, bit=1)
    }
    const _Float16* xp = xpb + 2 * xIterStep;  // next load: steps (t+4, t+5)
    __syncthreads();

#pragma unroll 1
    for (int t = 0; t < T_; t += 2) {
        {   // even step s=t: read s_h[0] -> write s_h[1], consume gates A
            h8 ah0 = *(const h8*)&s_h[0][offh[0]];
            h8 ah1 = *(const h8*)&s_h[0][offh[1]];
            h8 ah2 = *(const h8*)&s_h[0][offh[2]];
            h8 ah3 = *(const h8*)&s_h[0][offh[3]];
            f4 hRa = z4, hRb = z4, hZa = z4, hZb = z4, hNa = sHn4, hNb = z4;
            hRa = MFMA16(ah0, bh[0][0], hRa, 0, 0, 0);
            hZa = MFMA16(ah0, bh[1][0], hZa, 0, 0, 0);
            hNa = MFMA16(ah0, bh[2][0], hNa, 0, 0, 0);
            hRb = MFMA16(ah2, bh[0][2], hRb, 0, 0, 0);
            hZb = MFMA16(ah2, bh[1][2], hZb, 0, 0, 0);
            hNb = MFMA16(ah2, bh[2][2], hNb, 0, 0, 0);
            hRa = MFMA16(ah1, bh[0][1], hRa, 0, 0, 0);
            hZa = MFMA16(ah1, bh[1][1], hZa, 0, 0, 0);
            hNa = MFMA16(ah1, bh[2][1], hNa, 0, 0, 0);
            hRb = MFMA16(ah3, bh[0][3], hRb, 0, 0, 0);
            hZb = MFMA16(ah3, bh[1][3], hZb, 0, 0, 0);
            hNb = MFMA16(ah3, bh[2][3], hNb, 0, 0, 0);
            float r = sigm(xrA + hRa[0] + hRb[0]);
            float z = sigm(xzA + hZa[0] + hZb[0]);
            float n = tanh_f(xnA + r * (hNa[0] + hNb[0]));
            float h = n + z * (hF - n);
            hF = h;
            s_h[1][offw0] = (_Float16)h;
            *op = (_Float16)h; op += ostep;
            if (t + 2 < T_) {   // next gate pair (t+2, t+3) from packed xv
                f4 aXr = sR4, aXz = sZ4, aXn = sXn4;
                aXr = MFMA16(xv0, bx[0][0], aXr, 0, 0, 0);
                aXz = MFMA16(xv0, bx[1][0], aXz, 0, 0, 0);
                aXn = MFMA16(xv0, bx[2][0], aXn, 0, 0, 0);
                aXr = MFMA16(xv1, bx[0][1], aXr, 0, 0, 0);
                aXz = MFMA16(xv1, bx[1][1], aXz, 0, 0, 0);
                aXn = MFMA16(xv1, bx[2][1], aXn, 0, 0, 0);
                nxrA = aXr[0]; nxzA = aXz[0]; nxnA = aXn[0];
                nxrB = aXr[2]; nxzB = aXz[2]; nxnB = aXn[2];
            }
            bar_lds();
        }
        {   // odd step s=t+1: read s_h[1] -> write s_h[0], consume gates B
            h8 ah0 = *(const h8*)&s_h[1][offh[0]];
            h8 ah1 = *(const h8*)&s_h[1][offh[1]];
            h8 ah2 = *(const h8*)&s_h[1][offh[2]];
            h8 ah3 = *(const h8*)&s_h[1][offh[3]];
            f4 hRa = z4, hRb = z4, hZa = z4, hZb = z4, hNa = sHn4, hNb = z4;
            hRa = MFMA16(ah0, bh[0][0], hRa, 0, 0, 0);
            hZa = MFMA16(ah0, bh[1][0], hZa, 0, 0, 0);
            hNa = MFMA16(ah0, bh[2][0], hNa, 0, 0, 0);
            hRb = MFMA16(ah2, bh[0][2], hRb, 0, 0, 0);
            hZb = MFMA16(ah2, bh[1][2], hZb, 0, 0, 0);
            hNb = MFMA16(ah2, bh[2][2], hNb, 0, 0, 0);
            hRa = MFMA16(ah1, bh[0][1], hRa, 0, 0, 0);
            hZa = MFMA16(ah1, bh[1][1], hZa, 0, 0, 0);
            hNa = MFMA16(ah1, bh[2][1], hNa, 0, 0, 0);
            hRb = MFMA16(ah3, bh[0][3], hRb, 0, 0, 0);
            hZb = MFMA16(ah3, bh[1][3], hZb, 0, 0, 0);
            hNb = MFMA16(ah3, bh[2][3], hNb, 0, 0, 0);
            float r = sigm(xrB + hRa[0] + hRb[0]);
            float z = sigm(xzB + hZa[0] + hZb[0]);
            float n = tanh_f(xnB + r * (hNa[0] + hNb[0]));
            float h = n + z * (hF - n);
            hF = h;
            s_h[0][offw0] = (_Float16)h;
            *op = (_Float16)h; op += ostep;
            // rotate gate pair; reload xv for (t+4, t+5)
            xrA = nxrA; xzA = nxzA; xnA = nxnA;
            xrB = nxrB; xzB = nxzB; xnB = nxnB;
            if (t + 4 < T_) {
                xv0 = *(const h8*)(xp);
                xv1 = *(const h8*)(xp + 32);
                xp += xIterStep;
            }
            bar_lds();
        }
    }
}

// ---------------- MFMA GEMM v4: per-block M=64, full N=384 (unchanged) ----------------
__launch_bounds__(256, 1)
__global__ void gemm_xw1(const _Float16* __restrict__ A,
                         const _Float16* __restrict__ Bw,
                         const float* __restrict__ bias,
                         _Float16* __restrict__ C) {
    __shared__ __align__(16) _Float16 sA[2][64 * 64];
    __shared__ __align__(16) _Float16 sB[2][384 * 64];
    const int tid  = threadIdx.x;
    const int lane = tid & 63;
    const int w    = tid >> 6;
    const int wm   = w & 1, wn = w >> 1;
    const int ln15 = lane & 15, lq = lane >> 4;
    const size_t m0 = (size_t)blockIdx.x * 64;

    f4 acc[2][12] = {};

    int aRow[2], aG[2], aOff[2];
#pragma unroll
    for (int k = 0; k < 2; k++) {
        int idx = k * 256 + tid;
        aRow[k] = idx >> 3; aG[k] = idx & 7;
        aOff[k] = aRow[k] * 64 + ((aG[k] ^ (aRow[k] & 7)) & 7) * 8;
    }
    int bRow[12], bG[12], bOff[12];
#pragma unroll
    for (int k = 0; k < 12; k++) {
        int idx = k * 256 + tid;
        bRow[k] = idx >> 3; bG[k] = idx & 7;
        bOff[k] = bRow[k] * 64 + ((bG[k] ^ (bRow[k] & 7)) & 7) * 8;
    }
    int offA[2][2], offB[12][2];
#pragma unroll
    for (int mt = 0; mt < 2; mt++)
#pragma unroll
        for (int kt = 0; kt < 2; kt++) {
            int row = wm * 32 + mt * 16 + ln15;
            offA[mt][kt] = row * 64 + (((kt * 4 + lq) ^ (row & 7)) & 7) * 8;
        }
#pragma unroll
    for (int nt = 0; nt < 12; nt++)
#pragma unroll
        for (int kt = 0; kt < 2; kt++) {
            int row = wn * 192 + nt * 16 + ln15;
            offB[nt][kt] = row * 64 + (((kt * 4 + lq) ^ (row & 7)) & 7) * 8;
        }

    {   // prologue: chunk 0 -> buf 0
        h8 av[2], bv[12];
#pragma unroll
        for (int k = 0; k < 2; k++) av[k] = *(const h8*)(A + (m0 + aRow[k]) * 256 + aG[k] * 8);
#pragma unroll
        for (int k = 0; k < 12; k++) bv[k] = *(const h8*)(Bw + (size_t)bRow[k] * 256 + bG[k] * 8);
#pragma unroll
        for (int k = 0; k < 2; k++) *(h8*)&sA[0][aOff[k]] = av[k];
#pragma unroll
        for (int k = 0; k < 12; k++) *(h8*)&sB[0][bOff[k]] = bv[k];
        bar_lds();
    }

#pragma unroll
    for (int c = 0; c < 4; c++) {
        const int cur = c & 1;
        h8 av[2], bv[12];
        if (c < 3) {
#pragma unroll
            for (int k = 0; k < 2; k++)
                av[k] = *(const h8*)(A + (m0 + aRow[k]) * 256 + (c + 1) * 64 + aG[k] * 8);
#pragma unroll
            for (int k = 0; k < 12; k++)
                bv[k] = *(const h8*)(Bw + (size_t)bRow[k] * 256 + (c + 1) * 64 + bG[k] * 8);
        }
#pragma unroll
        for (int kt = 0; kt < 2; kt++) {
            h8 af0 = *(const h8*)&sA[cur][offA[0][kt]];
            h8 af1 = *(const h8*)&sA[cur][offA[1][kt]];
#pragma unroll
            for (int nt = 0; nt < 12; nt++) {
                h8 bf = *(const h8*)&sB[cur][offB[nt][kt]];
                acc[0][nt] = MFMA16(af0, bf, acc[0][nt], 0, 0, 0);
                acc[1][nt] = MFMA16(af1, bf, acc[1][nt], 0, 0, 0);
            }
        }
        if (c < 3) {
#pragma unroll
            for (int k = 0; k < 2; k++) *(h8*)&sA[cur ^ 1][aOff[k]] = av[k];
#pragma unroll
            for (int k = 0; k < 12; k++) *(h8*)&sB[cur ^ 1][bOff[k]] = bv[k];
            bar_lds();
        }
    }
#pragma unroll
    for (int nt = 0; nt < 12; nt++) {
        int col = wn * 192 + nt * 16 + ln15;
        float bb = bias[col];
        int pcol = (col < 256) ? ((col & 127) * 2 + (col >> 7)) : col;
#pragma unroll
        for (int mt = 0; mt < 2; mt++) {
            size_t row = m0 + wm * 32 + mt * 16 + lq * 4;
#pragma unroll
            for (int reg = 0; reg < 4; reg++)
                C[(row + reg) * G_ + pcol] = (_Float16)(acc[mt][nt][reg] + bb);
        }
    }
}

// ---------------- Layer-1 fwd scan: 4 waves x 2 column-tiles (256 threads) ----------------
// Per wave: cols [32w,32w+16) and [32w+16,32w+32). A-frag ds_reads shared across
// the two col-tiles (halved per SIMD); barrier across 4 waves; 24 independent
// MFMAs give in-wave ILP. Gates register-prefetched from xw1 (2 steps ahead).
__launch_bounds__(256, 1)
__global__ void scan_l1(const _Float16* __restrict__ xw1,
                        const float* __restrict__ Whh,
                        const float* __restrict__ bhh,
                        float* __restrict__ h1f) {
    __shared__ __align__(16) _Float16 s_h[2][16 * 128];

    const int tid  = threadIdx.x;
    const int lane = tid & 63;
    const int w    = tid >> 6;           // 0..3
    const int b0   = blockIdx.x * 4;

    for (int i = tid; i < 2 * 16 * 128; i += 256) ((_Float16*)s_h)[i] = (_Float16)0.f;

    const int ln15 = lane & 15;
    const int lq   = lane >> 4;
    int col[2];
    col[0] = 32 * w + ln15;
    col[1] = 32 * w + 16 + ln15;

    h8 bh[3][4][2];
    float bhhF[3][2];
#pragma unroll
    for (int g = 0; g < 3; g++)
#pragma unroll
        for (int ct = 0; ct < 2; ct++) {
            int n = g * H_ + col[ct];
            bhhF[g][ct] = bhh[n];
#pragma unroll
            for (int kt = 0; kt < 4; kt++)
                bh[g][kt][ct] = load_w8(Whh + (size_t)n * H_ + kt * 32 + lq * 8);
        }
    const int arow = ln15 & 12;
    int offh[4];
#pragma unroll
    for (int kt = 0; kt < 4; kt++)
        offh[kt] = arow * 128 + (((kt * 4 + lq) ^ arow) & 15) * 8;
    const int row0 = lq * 4;
    int offw[2];
#pragma unroll
    for (int ct = 0; ct < 2; ct++)
        offw[ct] = row0 * 128 + ((((col[ct] >> 3) ^ row0) & 15)) * 8 + (col[ct] & 7);

    const f4 z4 = (f4){0.f, 0.f, 0.f, 0.f};
    f4 sR[2], sZ[2], sN[2];
#pragma unroll
    for (int ct = 0; ct < 2; ct++) {
        sR[ct] = (f4){bhhF[0][ct], bhhF[0][ct], bhhF[0][ct], bhhF[0][ct]};
        sZ[ct] = (f4){bhhF[1][ct], bhhF[1][ct], bhhF[1][ct], bhhF[1][ct]};
        sN[ct] = (f4){bhhF[2][ct], bhhF[2][ct], bhhF[2][ct], bhhF[2][ct]};
    }

    const _Float16* rzbase[2];
    const _Float16* nbase[2];
#pragma unroll
    for (int ct = 0; ct < 2; ct++) {
        rzbase[ct] = xw1 + ((size_t)(b0 + lq) * T_) * G_ + 2 * col[ct];
        nbase[ct]  = xw1 + ((size_t)(b0 + lq) * T_) * G_ + 256 + col[ct];
    }

    __syncthreads();

    float hF[2] = {0.f, 0.f};
    h2 rzA[2], rzB[2];
    _Float16 nA[2], nB[2];
    const _Float16* rzP2[2];
    const _Float16* nP2[2];
    const _Float16* rzP3[2];
    const _Float16* nP3[2];
#pragma unroll
    for (int ct = 0; ct < 2; ct++) {
        rzA[ct] = *(const h2*)(rzbase[ct]);
        rzB[ct] = *(const h2*)(rzbase[ct] + G_);
        nA[ct]  = *nbase[ct];
        nB[ct]  = *(nbase[ct] + G_);
        rzP2[ct] = rzbase[ct] + 2 * G_;
        nP2[ct]  = nbase[ct]  + 2 * G_;
        rzP3[ct] = rzbase[ct] + 3 * G_;
        nP3[ct]  = nbase[ct]  + 3 * G_;
    }

#pragma unroll 1
    for (int s = 0; s < T_; s += 2) {
        {   // even step: read s_h[0] -> write s_h[1]
            h8 ah0 = *(const h8*)&s_h[0][offh[0]];
            h8 ah1 = *(const h8*)&s_h[0][offh[1]];
            h8 ah2 = *(const h8*)&s_h[0][offh[2]];
            h8 ah3 = *(const h8*)&s_h[0][offh[3]];
            f4 hRa[2], hRb[2], hZa[2], hZb[2], hNa[2], hNb[2];
            float xr[2], xz[2], xn[2];
#pragma unroll
            for (int ct = 0; ct < 2; ct++) {
                xr[ct] = (float)rzA[ct][0]; xz[ct] = (float)rzA[ct][1]; xn[ct] = (float)nA[ct];
                if (s + 2 < T_) {
                    rzA[ct] = *(const h2*)rzP2[ct];
                    nA[ct]  = *nP2[ct];
                    rzP2[ct] += 2 * G_; nP2[ct] += 2 * G_;
                }
                hRa[ct] = sR[ct]; hRb[ct] = z4; hZa[ct] = sZ[ct]; hZb[ct] = z4; hNa[ct] = sN[ct]; hNb[ct] = z4;
                hRa[ct] = MFMA16(ah0, bh[0][0][ct], hRa[ct], 0, 0, 0);
                hZa[ct] = MFMA16(ah0, bh[1][0][ct], hZa[ct], 0, 0, 0);
                hNa[ct] = MFMA16(ah0, bh[2][0][ct], hNa[ct], 0, 0, 0);
                hRb[ct] = MFMA16(ah2, bh[0][2][ct], hRb[ct], 0, 0, 0);
                hZb[ct] = MFMA16(ah2, bh[1][2][ct], hZb[ct], 0, 0, 0);
                hNb[ct] = MFMA16(ah2, bh[2][2][ct], hNb[ct], 0, 0, 0);
                hRa[ct] = MFMA16(ah1, bh[0][1][ct], hRa[ct], 0, 0, 0);
                hZa[ct] = MFMA16(ah1, bh[1][1][ct], hZa[ct], 0, 0, 0);
                hNa[ct] = MFMA16(ah1, bh[2][1][ct], hNa[ct], 0, 0, 0);
                hRb[ct] = MFMA16(ah3, bh[0][3][ct], hRb[ct], 0, 0, 0);
                hZb[ct] = MFMA16(ah3, bh[1][3][ct], hZb[ct], 0, 0, 0);
                hNb[ct] = MFMA16(ah3, bh[2][3][ct], hNb[ct], 0, 0, 0);
            }
#pragma unroll
            for (int ct = 0; ct < 2; ct++) {
                float r = sigm(xr[ct] + hRa[ct][0] + hRb[ct][0]);
                float z = sigm(xz[ct] + hZa[ct][0] + hZb[ct][0]);
                float n = tanh_f(xn[ct] + r * (hNa[ct][0] + hNb[ct][0]));
                float h = n + z * (hF[ct] - n);
                hF[ct] = h;
                s_h[1][offw[ct]] = (_Float16)h;
            }
            bar_lds();
        }
        {   // odd step: read s_h[1] -> write s_h[0]
            h8 ah0 = *(const h8*)&s_h[1][offh[0]];
            h8 ah1 = *(const h8*)&s_h[1][offh[1]];
            h8 ah2 = *(const h8*)&s_h[1][offh[2]];
            h8 ah3 = *(const h8*)&s_h[1][offh[3]];
            f4 hRa[2], hRb[2], hZa[2], hZb[2], hNa[2], hNb[2];
            float xr[2], xz[2], xn[2];
#pragma unroll
            for (int ct = 0; ct < 2; ct++) {
                xr[ct] = (float)rzB[ct][0]; xz[ct] = (float)rzB[ct][1]; xn[ct] = (float)nB[ct];
                if (s + 3 < T_) {
                    rzB[ct] = *(const h2*)rzP3[ct];
                    nB[ct]  = *nP3[ct];
                    rzP3[ct] += 2 * G_; nP3[ct] += 2 * G_;
                }
                hRa[ct] = sR[ct]; hRb[ct] = z4; hZa[ct] = sZ[ct]; hZb[ct] = z4; hNa[ct] = sN[ct]; hNb[ct] = z4;
                hRa[ct] = MFMA16(ah0, bh[0][0][ct], hRa[ct], 0, 0, 0);
                hZa[ct] = MFMA16(ah0, bh[1][0][ct], hZa[ct], 0, 0, 0);
                hNa[ct] = MFMA16(ah0, bh[2][0][ct], hNa[ct], 0, 0, 0);
                hRb[ct] = MFMA16(ah2, bh[0][2][ct], hRb[ct], 0, 0, 0);
                hZb[ct] = MFMA16(ah2, bh[1][2][ct], hZb[ct], 0, 0, 0);
                hNb[ct] = MFMA16(ah2, bh[2][2][ct], hNb[ct], 0, 0, 0);
                hRa[ct] = MFMA16(ah1, bh[0][1][ct], hRa[ct], 0, 0, 0);
                hZa[ct] = MFMA16(ah1, bh[1][1][ct], hZa[ct], 0, 0, 0);
                hNa[ct] = MFMA16(ah1, bh[2][1][ct], hNa[ct], 0, 0, 0);
                hRb[ct] = MFMA16(ah3, bh[0][3][ct], hRb[ct], 0, 0, 0);
                hZb[ct] = MFMA16(ah3, bh[1][3][ct], hZb[ct], 0, 0, 0);
                hNb[ct] = MFMA16(ah3, bh[2][3][ct], hNb[ct], 0, 0, 0);
            }
#pragma unroll
            for (int ct = 0; ct < 2; ct++) {
                float r = sigm(xr[ct] + hRa[ct][0] + hRb[ct][0]);
                float z = sigm(xz[ct] + hZa[ct][0] + hZb[ct][0]);
                float n = tanh_f(xn[ct] + r * (hNa[ct][0] + hNb[ct][0]));
                float h = n + z * (hF[ct] - n);
                hF[ct] = h;
                s_h[0][offw[ct]] = (_Float16)h;
            }
            bar_lds();
        }
    }
#pragma unroll
    for (int ct = 0; ct < 2; ct++)
        h1f[(size_t)(b0 + lq) * H_ + col[ct]] = hF[ct];
}

// ---------------- Tail: layer-1 bwd single step + relu + FC (unchanged) ----------------
__launch_bounds__(384)
__global__ void final_k(const _Float16* __restrict__ out0,
                        const float* __restrict__ h1f,
                        const __half2* __restrict__ w1b,
                        const float* __restrict__ bih1b, const float* __restrict__ bhh1b,
                        const float* __restrict__ fcw, const float* __restrict__ fcb,
                        float* __restrict__ out) {
    __shared__ __align__(16) float s_x1[HC];
    __shared__ __align__(16) float s_xw[G_];
    __shared__ __align__(16) float s_hc[HC];
    __shared__ float s_red[8];
    const int tid = threadIdx.x;
    const int b = blockIdx.x;
    if (tid < HC)
        s_x1[tid] = (float)out0[((size_t)b * T_ + (T_ - 1)) * HC + tid];
    __syncthreads();
    {
        float acc0 = 0.f, acc1 = 0.f;
        const float2* xv = (const float2*)s_x1;
#pragma unroll 8
        for (int k2 = 0; k2 < 128; k2 += 2) {
            float2 w0 = __half22float2(w1b[k2 * G_ + tid]);
            float2 w1 = __half22float2(w1b[(k2 + 1) * G_ + tid]);
            float2 a0 = xv[k2], a1 = xv[k2 + 1];
            acc0 += a0.x * w0.x + a0.y * w0.y;
            acc1 += a1.x * w1.x + a1.y * w1.y;
        }
        s_xw[tid] = bih1b[tid] + acc0 + acc1;
    }
    __syncthreads();
    if (tid < H_) {
        int j = tid;
        float rg = sigm(s_xw[j] + bhh1b[j]);
        float zg = sigm(s_xw[H_ + j] + bhh1b[H_ + j]);
        float ng = tanh_f(s_xw[2 * H_ + j] + rg * bhh1b[2 * H_ + j]);
        float hb = (1.f - zg) * ng;
        s_hc[H_ + j] = fmaxf(hb, 0.f);
        s_hc[j] = fmaxf(h1f[(size_t)b * H_ + j], 0.f);
    }
    __syncthreads();
    if (tid < HC) {
        float hv = s_hc[tid];
        float p0 = hv * fcw[tid];
        float p1 = hv * fcw[HC + tid];
#pragma unroll
        for (int off = 32; off; off >>= 1) {
            p0 += __shfl_down(p0, off);
            p1 += __shfl_down(p1, off);
        }
        if ((tid & 63) == 0) { s_red[(tid >> 6) * 2] = p0; s_red[(tid >> 6) * 2 + 1] = p1; }
    }
    __syncthreads();
    if (tid == 0) {
        out[b * 2 + 0] = fcb[0] + s_red[0] + s_red[2] + s_red[4] + s_red[6];
        out[b * 2 + 1] = fcb[1] + s_red[1] + s_red[3] + s_red[5] + s_red[7];
    }
}

extern "C" void kernel_launch(void* const* d_in, const int* in_sizes, int n_in,
                              void* d_out, int out_size, void* d_ws, size_t ws_size,
                              hipStream_t stream) {
    (void)in_sizes; (void)n_in; (void)out_size; (void)ws_size;
    const float* x     = (const float*)d_in[0];
    const float* Wih0f = (const float*)d_in[1];
    const float* Whh0f = (const float*)d_in[2];
    const float* bih0f = (const float*)d_in[3];
    const float* bhh0f = (const float*)d_in[4];
    const float* Wih0b = (const float*)d_in[5];
    const float* Whh0b = (const float*)d_in[6];
    const float* bih0b = (const float*)d_in[7];
    const float* bhh0b = (const float*)d_in[8];
    const float* Wih1f = (const float*)d_in[9];
    const float* Whh1f = (const float*)d_in[10];
    const float* bih1f = (const float*)d_in[11];
    const float* bhh1f = (const float*)d_in[12];
    const float* Wih1b = (const float*)d_in[13];
    const float* bih1b = (const float*)d_in[15];
    const float* bhh1b = (const float*)d_in[16];
    const float* fcw   = (const float*)d_in[17];
    const float* fcb   = (const float*)d_in[18];

    char* ws = (char*)d_ws;
    _Float16* out0 = (_Float16*)(ws + O_OUT0);
    _Float16* xw1  = (_Float16*)(ws + O_XW1);
    _Float16* x16  = (_Float16*)(ws + O_X16);
    __half2*  wp   = (__half2*)(ws + O_WP);
    float*    h1f  = (float*)(ws + O_H1F);
    _Float16* wf16 = (_Float16*)(ws + O_WF16);
    float*    out  = (float*)d_out;

    prep<<<4336, 256, 0, stream>>>(x, x16, Wih1f, wf16, Wih1b, wp);

    scan_l0<<<dim3(64, 2), 512, 0, stream>>>(x16, Wih0f, Whh0f, bih0f, bhh0f,
                                             Wih0b, Whh0b, bih0b, bhh0b, out0);

    gemm_xw1<<<2048, 256, 0, stream>>>(out0, wf16, bih1f, xw1);

    scan_l1<<<64, 256, 0, stream>>>(xw1, Whh1f, bhh1f, h1f);

    final_k<<<256, 384, 0, stream>>>(out0, h1f, wp, bih1b, bhh1b, fcw, fcb, out);
}

// Round 14
// 562.438 us; speedup vs baseline: 1.5897x; 1.1408x over previous
//
#include <hip/hip_runtime.h>
#include <hip/hip_fp16.h>

#define B_  256
#define T_  512
#define I_  64
#define H_  128
#define G_  384
#define HC  256

#define O_OUT0 0ull
#define O_XW1  67108864ull
#define O_X16  O_XW1
#define O_WP   167772160ull
#define O_H1F  (O_WP + 196608ull)
#define O_WF16 (O_H1F + 131072ull)

typedef _Float16 h8 __attribute__((ext_vector_type(8)));
typedef _Float16 h2 __attribute__((ext_vector_type(2)));
typedef float    f4 __attribute__((ext_vector_type(4)));

#define MFMA16 __builtin_amdgcn_mfma_f32_16x16x32_f16

__device__ __forceinline__ float sigm(float x)   { return __builtin_amdgcn_rcpf(1.f + __expf(-x)); }
__device__ __forceinline__ float tanh_f(float x) { return 1.f - 2.f * __builtin_amdgcn_rcpf(1.f + __expf(2.f * x)); }

__device__ __forceinline__ void bar_lds() {
    asm volatile("s_waitcnt lgkmcnt(0)\n\ts_barrier" ::: "memory");
}

__device__ __forceinline__ h8 load_w8(const float* src) {
    f4 a = *(const f4*)src;
    f4 b = *(const f4*)(src + 4);
    h8 v;
    v[0]=(_Float16)a[0]; v[1]=(_Float16)a[1]; v[2]=(_Float16)a[2]; v[3]=(_Float16)a[3];
    v[4]=(_Float16)b[0]; v[5]=(_Float16)b[1]; v[6]=(_Float16)b[2]; v[7]=(_Float16)b[3];
    return v;
}

// Fused prep: x->fp16 (4096 blocks), Wih1f->fp16 (48), Wih1b pack-T (192).
__global__ void prep(const float* __restrict__ x, _Float16* __restrict__ x16,
                     const float* __restrict__ Wf, _Float16* __restrict__ wf16,
                     const float* __restrict__ W1b, __half2* __restrict__ wp) {
    const int bid = blockIdx.x;
    const int tid = threadIdx.x;
    if (bid < 4096) {
        int i = bid * 256 + tid;
        const float* s = x + (size_t)i * 8;
        f4 a = *(const f4*)s, b = *(const f4*)(s + 4);
        h8 v;
        v[0]=(_Float16)a[0]; v[1]=(_Float16)a[1]; v[2]=(_Float16)a[2]; v[3]=(_Float16)a[3];
        v[4]=(_Float16)b[0]; v[5]=(_Float16)b[1]; v[6]=(_Float16)b[2]; v[7]=(_Float16)b[3];
        *(h8*)(x16 + (size_t)i * 8) = v;
    } else if (bid < 4144) {
        int i = (bid - 4096) * 256 + tid;
        const float* s = Wf + (size_t)i * 8;
        f4 a = *(const f4*)s, b = *(const f4*)(s + 4);
        h8 v;
        v[0]=(_Float16)a[0]; v[1]=(_Float16)a[1]; v[2]=(_Float16)a[2]; v[3]=(_Float16)a[3];
        v[4]=(_Float16)b[0]; v[5]=(_Float16)b[1]; v[6]=(_Float16)b[2]; v[7]=(_Float16)b[3];
        *(h8*)(wf16 + (size_t)i * 8) = v;
    } else {
        int i = (bid - 4144) * 256 + tid;
        int c = i % G_;
        int k2 = i / G_;
        wp[i] = __halves2half2(__float2half(W1b[c * 256 + 2 * k2]),
                               __float2half(W1b[c * 256 + 2 * k2 + 1]));
    }
}

// ---------------- Layer-0 scan: 4 rows/block + 2-timestep-packed x-MFMAs ----------------
// Batches at A-rows {0,4,8,12}; valid h C-data = reg 0 of every lane.
// x-part packing: A-row r -> batch (r>>2), time-slot bit (r>>1)&1. One 6-MFMA set
// yields gates for TWO steps: reg0 (bit=0) and reg2 (bit=1).
// A-frag h reads broadcast via row ln15&12 (conflict-free). Flat MFMA chains.
__launch_bounds__(512, 1)
__global__ void scan_l0(const _Float16* __restrict__ x16,
                        const float* __restrict__ Wih_f, const float* __restrict__ Whh_f,
                        const float* __restrict__ bih_f, const float* __restrict__ bhh_f,
                        const float* __restrict__ Wih_b, const float* __restrict__ Whh_b,
                        const float* __restrict__ bih_b, const float* __restrict__ bhh_b,
                        _Float16* __restrict__ out0) {
    __shared__ __align__(16) _Float16 s_h[2][16 * 128];

    const int tid  = threadIdx.x;
    const int lane = tid & 63;
    const int w    = tid >> 6;           // 0..7
    const int dir  = blockIdx.y;
    const int b0   = blockIdx.x * 4;

    const float* Wih = dir ? Wih_b : Wih_f;
    const float* Whh = dir ? Whh_b : Whh_f;
    const float* bih = dir ? bih_b : bih_f;
    const float* bhh = dir ? bhh_b : bhh_f;

    for (int i = tid; i < 2 * 16 * 128; i += 512) ((_Float16*)s_h)[i] = (_Float16)0.f;

    const int ln15 = lane & 15;
    const int lq   = lane >> 4;
    const int col  = 16 * w + ln15;

    h8 bh[3][4], bx[3][2];
    float seedR = bih[col] + bhh[col];
    float seedZ = bih[H_ + col] + bhh[H_ + col];
    float bihN  = bih[2 * H_ + col];
    float bhhN  = bhh[2 * H_ + col];
#pragma unroll
    for (int g = 0; g < 3; g++) {
        int n = g * H_ + col;
#pragma unroll
        for (int kt = 0; kt < 4; kt++) bh[g][kt] = load_w8(Whh + (size_t)n * H_ + kt * 32 + lq * 8);
#pragma unroll
        for (int kt = 0; kt < 2; kt++) bx[g][kt] = load_w8(Wih + (size_t)n * I_ + kt * 32 + lq * 8);
    }
    const int arow = ln15 & 12;          // broadcast A-read row (conflict-free)
    int offh[4];
#pragma unroll
    for (int kt = 0; kt < 4; kt++)
        offh[kt] = arow * 128 + (((kt * 4 + lq) ^ arow) & 15) * 8;
    const int row0  = lq * 4;
    const int offw0 = row0 * 128 + ((((col >> 3) ^ row0) & 15)) * 8 + (col & 7);

    const f4 z4 = (f4){0.f, 0.f, 0.f, 0.f};
    const f4 sR4 = (f4){seedR, seedR, seedR, seedR};
    const f4 sZ4 = (f4){seedZ, seedZ, seedZ, seedZ};
    const f4 sXn4 = (f4){bihN, bihN, bihN, bihN};
    const f4 sHn4 = (f4){bhhN, bhhN, bhhN, bhhN};

    // x packed-lane pointer: batch = b0 + (ln15>>2); time bit = (ln15>>1)&1.
    const int tbit = (ln15 >> 1) & 1;
    const _Float16* xpb = x16 + ((size_t)(b0 + (ln15 >> 2)) * T_ + (dir ? (T_ - 1 - tbit) : tbit)) * I_ + lq * 8;
    const int xIterStep = dir ? -(2 * I_) : (2 * I_);   // advance 2 timesteps per iter

    _Float16* op = out0 + ((size_t)(b0 + lq) * T_ + (dir ? (T_ - 1) : 0)) * HC + dir * H_ + col;
    const int ostep = dir ? -HC : HC;

    float hF = 0.f;
    float xrA, xzA, xnA, xrB, xzB, xnB;
    float nxrA, nxzA, nxnA, nxrB, nxzB, nxnB;
    h8 xv0, xv1;
    {   // prologue: gates(0,1) from packed x(0,1); issue xv <- x(2,3)
        h8 xc0 = *(const h8*)(xpb);
        h8 xc1 = *(const h8*)(xpb + 32);
        xv0 = *(const h8*)(xpb + xIterStep);
        xv1 = *(const h8*)(xpb + xIterStep + 32);
        f4 aXr = sR4, aXz = sZ4, aXn = sXn4;
        aXr = MFMA16(xc0, bx[0][0], aXr, 0, 0, 0);
        aXz = MFMA16(xc0, bx[1][0], aXz, 0, 0, 0);
        aXn = MFMA16(xc0, bx[2][0], aXn, 0, 0, 0);
        aXr = MFMA16(xc1, bx[0][1], aXr, 0, 0, 0);
        aXz = MFMA16(xc1, bx[1][1], aXz, 0, 0, 0);
        aXn = MFMA16(xc1, bx[2][1], aXn, 0, 0, 0);
        xrA = aXr[0]; xzA = aXz[0]; xnA = aXn[0];
        xrB = aXr[2]; xzB = aXz[2]; xnB = aXn[2];
    }
    const _Float16* xp = xpb + 2 * xIterStep;
    __syncthreads();

#pragma unroll 1
    for (int t = 0; t < T_; t += 2) {
        {   // even step s=t: read s_h[0] -> write s_h[1], consume gates A
            h8 ah0 = *(const h8*)&s_h[0][offh[0]];
            h8 ah1 = *(const h8*)&s_h[0][offh[1]];
            h8 ah2 = *(const h8*)&s_h[0][offh[2]];
            h8 ah3 = *(const h8*)&s_h[0][offh[3]];
            f4 hRa = z4, hRb = z4, hZa = z4, hZb = z4, hNa = sHn4, hNb = z4;
            hRa = MFMA16(ah0, bh[0][0], hRa, 0, 0, 0);
            hZa = MFMA16(ah0, bh[1][0], hZa, 0, 0, 0);
            hNa = MFMA16(ah0, bh[2][0], hNa, 0, 0, 0);
            hRb = MFMA16(ah2, bh[0][2], hRb, 0, 0, 0);
            hZb = MFMA16(ah2, bh[1][2], hZb, 0, 0, 0);
            hNb = MFMA16(ah2, bh[2][2], hNb, 0, 0, 0);
            hRa = MFMA16(ah1, bh[0][1], hRa, 0, 0, 0);
            hZa = MFMA16(ah1, bh[1][1], hZa, 0, 0, 0);
            hNa = MFMA16(ah1, bh[2][1], hNa, 0, 0, 0);
            hRb = MFMA16(ah3, bh[0][3], hRb, 0, 0, 0);
            hZb = MFMA16(ah3, bh[1][3], hZb, 0, 0, 0);
            hNb = MFMA16(ah3, bh[2][3], hNb, 0, 0, 0);
            float r = sigm(xrA + hRa[0] + hRb[0]);
            float z = sigm(xzA + hZa[0] + hZb[0]);
            float n = tanh_f(xnA + r * (hNa[0] + hNb[0]));
            float h = n + z * (hF - n);
            hF = h;
            s_h[1][offw0] = (_Float16)h;
            *op = (_Float16)h; op += ostep;
            if (t + 2 < T_) {   // next gate pair (t+2, t+3) from packed xv
                f4 aXr = sR4, aXz = sZ4, aXn = sXn4;
                aXr = MFMA16(xv0, bx[0][0], aXr, 0, 0, 0);
                aXz = MFMA16(xv0, bx[1][0], aXz, 0, 0, 0);
                aXn = MFMA16(xv0, bx[2][0], aXn, 0, 0, 0);
                aXr = MFMA16(xv1, bx[0][1], aXr, 0, 0, 0);
                aXz = MFMA16(xv1, bx[1][1], aXz, 0, 0, 0);
                aXn = MFMA16(xv1, bx[2][1], aXn, 0, 0, 0);
                nxrA = aXr[0]; nxzA = aXz[0]; nxnA = aXn[0];
                nxrB = aXr[2]; nxzB = aXz[2]; nxnB = aXn[2];
            }
            bar_lds();
        }
        {   // odd step s=t+1: read s_h[1] -> write s_h[0], consume gates B
            h8 ah0 = *(const h8*)&s_h[1][offh[0]];
            h8 ah1 = *(const h8*)&s_h[1][offh[1]];
            h8 ah2 = *(const h8*)&s_h[1][offh[2]];
            h8 ah3 = *(const h8*)&s_h[1][offh[3]];
            f4 hRa = z4, hRb = z4, hZa = z4, hZb = z4, hNa = sHn4, hNb = z4;
            hRa = MFMA16(ah0, bh[0][0], hRa, 0, 0, 0);
            hZa = MFMA16(ah0, bh[1][0], hZa, 0, 0, 0);
            hNa = MFMA16(ah0, bh[2][0], hNa, 0, 0, 0);
            hRb = MFMA16(ah2, bh[0][2], hRb, 0, 0, 0);
            hZb = MFMA16(ah2, bh[1][2], hZb, 0, 0, 0);
            hNb = MFMA16(ah2, bh[2][2], hNb, 0, 0, 0);
            hRa = MFMA16(ah1, bh[0][1], hRa, 0, 0, 0);
            hZa = MFMA16(ah1, bh[1][1], hZa, 0, 0, 0);
            hNa = MFMA16(ah1, bh[2][1], hNa, 0, 0, 0);
            hRb = MFMA16(ah3, bh[0][3], hRb, 0, 0, 0);
            hZb = MFMA16(ah3, bh[1][3], hZb, 0, 0, 0);
            hNb = MFMA16(ah3, bh[2][3], hNb, 0, 0, 0);
            float r = sigm(xrB + hRa[0] + hRb[0]);
            float z = sigm(xzB + hZa[0] + hZb[0]);
            float n = tanh_f(xnB + r * (hNa[0] + hNb[0]));
            float h = n + z * (hF - n);
            hF = h;
            s_h[0][offw0] = (_Float16)h;
            *op = (_Float16)h; op += ostep;
            xrA = nxrA; xzA = nxzA; xnA = nxnA;
            xrB = nxrB; xzB = nxzB; xnB = nxnB;
            if (t + 4 < T_) {
                xv0 = *(const h8*)(xp);
                xv1 = *(const h8*)(xp + 32);
                xp += xIterStep;
            }
            bar_lds();
        }
    }
}

// ---------------- MFMA GEMM v4: per-block M=64, full N=384 (unchanged) ----------------
__launch_bounds__(256, 1)
__global__ void gemm_xw1(const _Float16* __restrict__ A,
                         const _Float16* __restrict__ Bw,
                         const float* __restrict__ bias,
                         _Float16* __restrict__ C) {
    __shared__ __align__(16) _Float16 sA[2][64 * 64];
    __shared__ __align__(16) _Float16 sB[2][384 * 64];
    const int tid  = threadIdx.x;
    const int lane = tid & 63;
    const int w    = tid >> 6;
    const int wm   = w & 1, wn = w >> 1;
    const int ln15 = lane & 15, lq = lane >> 4;
    const size_t m0 = (size_t)blockIdx.x * 64;

    f4 acc[2][12] = {};

    int aRow[2], aG[2], aOff[2];
#pragma unroll
    for (int k = 0; k < 2; k++) {
        int idx = k * 256 + tid;
        aRow[k] = idx >> 3; aG[k] = idx & 7;
        aOff[k] = aRow[k] * 64 + ((aG[k] ^ (aRow[k] & 7)) & 7) * 8;
    }
    int bRow[12], bG[12], bOff[12];
#pragma unroll
    for (int k = 0; k < 12; k++) {
        int idx = k * 256 + tid;
        bRow[k] = idx >> 3; bG[k] = idx & 7;
        bOff[k] = bRow[k] * 64 + ((bG[k] ^ (bRow[k] & 7)) & 7) * 8;
    }
    int offA[2][2], offB[12][2];
#pragma unroll
    for (int mt = 0; mt < 2; mt++)
#pragma unroll
        for (int kt = 0; kt < 2; kt++) {
            int row = wm * 32 + mt * 16 + ln15;
            offA[mt][kt] = row * 64 + (((kt * 4 + lq) ^ (row & 7)) & 7) * 8;
        }
#pragma unroll
    for (int nt = 0; nt < 12; nt++)
#pragma unroll
        for (int kt = 0; kt < 2; kt++) {
            int row = wn * 192 + nt * 16 + ln15;
            offB[nt][kt] = row * 64 + (((kt * 4 + lq) ^ (row & 7)) & 7) * 8;
        }

    {   // prologue: chunk 0 -> buf 0
        h8 av[2], bv[12];
#pragma unroll
        for (int k = 0; k < 2; k++) av[k] = *(const h8*)(A + (m0 + aRow[k]) * 256 + aG[k] * 8);
#pragma unroll
        for (int k = 0; k < 12; k++) bv[k] = *(const h8*)(Bw + (size_t)bRow[k] * 256 + bG[k] * 8);
#pragma unroll
        for (int k = 0; k < 2; k++) *(h8*)&sA[0][aOff[k]] = av[k];
#pragma unroll
        for (int k = 0; k < 12; k++) *(h8*)&sB[0][bOff[k]] = bv[k];
        bar_lds();
    }

#pragma unroll
    for (int c = 0; c < 4; c++) {
        const int cur = c & 1;
        h8 av[2], bv[12];
        if (c < 3) {
#pragma unroll
            for (int k = 0; k < 2; k++)
                av[k] = *(const h8*)(A + (m0 + aRow[k]) * 256 + (c + 1) * 64 + aG[k] * 8);
#pragma unroll
            for (int k = 0; k < 12; k++)
                bv[k] = *(const h8*)(Bw + (size_t)bRow[k] * 256 + (c + 1) * 64 + bG[k] * 8);
        }
#pragma unroll
        for (int kt = 0; kt < 2; kt++) {
            h8 af0 = *(const h8*)&sA[cur][offA[0][kt]];
            h8 af1 = *(const h8*)&sA[cur][offA[1][kt]];
#pragma unroll
            for (int nt = 0; nt < 12; nt++) {
                h8 bf = *(const h8*)&sB[cur][offB[nt][kt]];
                acc[0][nt] = MFMA16(af0, bf, acc[0][nt], 0, 0, 0);
                acc[1][nt] = MFMA16(af1, bf, acc[1][nt], 0, 0, 0);
            }
        }
        if (c < 3) {
#pragma unroll
            for (int k = 0; k < 2; k++) *(h8*)&sA[cur ^ 1][aOff[k]] = av[k];
#pragma unroll
            for (int k = 0; k < 12; k++) *(h8*)&sB[cur ^ 1][bOff[k]] = bv[k];
            bar_lds();
        }
    }
#pragma unroll
    for (int nt = 0; nt < 12; nt++) {
        int col = wn * 192 + nt * 16 + ln15;
        float bb = bias[col];
        int pcol = (col < 256) ? ((col & 127) * 2 + (col >> 7)) : col;
#pragma unroll
        for (int mt = 0; mt < 2; mt++) {
            size_t row = m0 + wm * 32 + mt * 16 + lq * 4;
#pragma unroll
            for (int reg = 0; reg < 4; reg++)
                C[(row + reg) * G_ + pcol] = (_Float16)(acc[mt][nt][reg] + bb);
        }
    }
}

// ---------------- Layer-1 fwd scan: 8 waves, 4 rows/block (R10 known-good) ----------------
// arow broadcast A-read + flat chains; gates register-prefetched from xw1 via
// running pointers (2 steps ahead), no LDS ring.
__launch_bounds__(512, 1)
__global__ void scan_l1(const _Float16* __restrict__ xw1,
                        const float* __restrict__ Whh,
                        const float* __restrict__ bhh,
                        float* __restrict__ h1f) {
    __shared__ __align__(16) _Float16 s_h[2][16 * 128];

    const int tid  = threadIdx.x;
    const int lane = tid & 63;
    const int w    = tid >> 6;
    const int b0   = blockIdx.x * 4;

    for (int i = tid; i < 2 * 16 * 128; i += 512) ((_Float16*)s_h)[i] = (_Float16)0.f;

    const int ln15 = lane & 15;
    const int lq   = lane >> 4;
    const int col  = 16 * w + ln15;

    h8 bh[3][4];
    float bhhF[3];
#pragma unroll
    for (int g = 0; g < 3; g++) {
        int n = g * H_ + col;
        bhhF[g] = bhh[n];
#pragma unroll
        for (int kt = 0; kt < 4; kt++) bh[g][kt] = load_w8(Whh + (size_t)n * H_ + kt * 32 + lq * 8);
    }
    const int arow = ln15 & 12;
    int offh[4];
#pragma unroll
    for (int kt = 0; kt < 4; kt++)
        offh[kt] = arow * 128 + (((kt * 4 + lq) ^ arow) & 15) * 8;
    const int row0  = lq * 4;
    const int offw0 = row0 * 128 + ((((col >> 3) ^ row0) & 15)) * 8 + (col & 7);

    const _Float16* rzbase = xw1 + ((size_t)(b0 + lq) * T_) * G_ + 2 * col;
    const _Float16* nbase  = xw1 + ((size_t)(b0 + lq) * T_) * G_ + 256 + col;

    const f4 z4 = (f4){0.f, 0.f, 0.f, 0.f};
    const f4 sR4 = (f4){bhhF[0], bhhF[0], bhhF[0], bhhF[0]};
    const f4 sZ4 = (f4){bhhF[1], bhhF[1], bhhF[1], bhhF[1]};
    const f4 sN4 = (f4){bhhF[2], bhhF[2], bhhF[2], bhhF[2]};

    __syncthreads();

    float hF = 0.f;
    h2 rzA = *(const h2*)(rzbase);
    h2 rzB = *(const h2*)(rzbase + G_);
    _Float16 nA = *nbase;
    _Float16 nB = *(nbase + G_);
    const _Float16* rzP2 = rzbase + 2 * G_;
    const _Float16* nP2  = nbase  + 2 * G_;
    const _Float16* rzP3 = rzbase + 3 * G_;
    const _Float16* nP3  = nbase  + 3 * G_;

#pragma unroll 1
    for (int s = 0; s < T_; s += 2) {
        {   // even step: read s_h[0] -> write s_h[1]
            h8 ah0 = *(const h8*)&s_h[0][offh[0]];
            h8 ah1 = *(const h8*)&s_h[0][offh[1]];
            h8 ah2 = *(const h8*)&s_h[0][offh[2]];
            h8 ah3 = *(const h8*)&s_h[0][offh[3]];
            float xr = (float)rzA[0], xz = (float)rzA[1], xn = (float)nA;
            if (s + 2 < T_) {
                rzA = *(const h2*)rzP2;
                nA  = *nP2;
                rzP2 += 2 * G_; nP2 += 2 * G_;
            }
            f4 hRa = sR4, hRb = z4, hZa = sZ4, hZb = z4, hNa = sN4, hNb = z4;
            hRa = MFMA16(ah0, bh[0][0], hRa, 0, 0, 0);
            hZa = MFMA16(ah0, bh[1][0], hZa, 0, 0, 0);
            hNa = MFMA16(ah0, bh[2][0], hNa, 0, 0, 0);
            hRb = MFMA16(ah2, bh[0][2], hRb, 0, 0, 0);
            hZb = MFMA16(ah2, bh[1][2], hZb, 0, 0, 0);
            hNb = MFMA16(ah2, bh[2][2], hNb, 0, 0, 0);
            hRa = MFMA16(ah1, bh[0][1], hRa, 0, 0, 0);
            hZa = MFMA16(ah1, bh[1][1], hZa, 0, 0, 0);
            hNa = MFMA16(ah1, bh[2][1], hNa, 0, 0, 0);
            hRb = MFMA16(ah3, bh[0][3], hRb, 0, 0, 0);
            hZb = MFMA16(ah3, bh[1][3], hZb, 0, 0, 0);
            hNb = MFMA16(ah3, bh[2][3], hNb, 0, 0, 0);
            float r = sigm(xr + hRa[0] + hRb[0]);
            float z = sigm(xz + hZa[0] + hZb[0]);
            float n = tanh_f(xn + r * (hNa[0] + hNb[0]));
            float h = n + z * (hF - n);
            hF = h;
            s_h[1][offw0] = (_Float16)h;
            bar_lds();
        }
        {   // odd step: read s_h[1] -> write s_h[0]
            h8 ah0 = *(const h8*)&s_h[1][offh[0]];
            h8 ah1 = *(const h8*)&s_h[1][offh[1]];
            h8 ah2 = *(const h8*)&s_h[1][offh[2]];
            h8 ah3 = *(const h8*)&s_h[1][offh[3]];
            float xr = (float)rzB[0], xz = (float)rzB[1], xn = (float)nB;
            if (s + 3 < T_) {
                rzB = *(const h2*)rzP3;
                nB  = *nP3;
                rzP3 += 2 * G_; nP3 += 2 * G_;
            }
            f4 hRa = sR4, hRb = z4, hZa = sZ4, hZb = z4, hNa = sN4, hNb = z4;
            hRa = MFMA16(ah0, bh[0][0], hRa, 0, 0, 0);
            hZa = MFMA16(ah0, bh[1][0], hZa, 0, 0, 0);
            hNa = MFMA16(ah0, bh[2][0], hNa, 0, 0, 0);
            hRb = MFMA16(ah2, bh[0][2], hRb, 0, 0, 0);
            hZb = MFMA16(ah2, bh[1][2], hZb, 0, 0, 0);
            hNb = MFMA16(ah2, bh[2][2], hNb, 0, 0, 0);
            hRa = MFMA16(ah1, bh[0][1], hRa, 0, 0, 0);
            hZa = MFMA16(ah1, bh[1][1], hZa, 0, 0, 0);
            hNa = MFMA16(ah1, bh[2][1], hNa, 0, 0, 0);
            hRb = MFMA16(ah3, bh[0][3], hRb, 0, 0, 0);
            hZb = MFMA16(ah3, bh[1][3], hZb, 0, 0, 0);
            hNb = MFMA16(ah3, bh[2][3], hNb, 0, 0, 0);
            float r = sigm(xr + hRa[0] + hRb[0]);
            float z = sigm(xz + hZa[0] + hZb[0]);
            float n = tanh_f(xn + r * (hNa[0] + hNb[0]));
            float h = n + z * (hF - n);
            hF = h;
            s_h[0][offw0] = (_Float16)h;
            bar_lds();
        }
    }
    h1f[(size_t)(b0 + lq) * H_ + col] = hF;
}

// ---------------- Tail: layer-1 bwd single step + relu + FC (unchanged) ----------------
__launch_bounds__(384)
__global__ void final_k(const _Float16* __restrict__ out0,
                        const float* __restrict__ h1f,
                        const __half2* __restrict__ w1b,
                        const float* __restrict__ bih1b, const float* __restrict__ bhh1b,
                        const float* __restrict__ fcw, const float* __restrict__ fcb,
                        float* __restrict__ out) {
    __shared__ __align__(16) float s_x1[HC];
    __shared__ __align__(16) float s_xw[G_];
    __shared__ __align__(16) float s_hc[HC];
    __shared__ float s_red[8];
    const int tid = threadIdx.x;
    const int b = blockIdx.x;
    if (tid < HC)
        s_x1[tid] = (float)out0[((size_t)b * T_ + (T_ - 1)) * HC + tid];
    __syncthreads();
    {
        float acc0 = 0.f, acc1 = 0.f;
        const float2* xv = (const float2*)s_x1;
#pragma unroll 8
        for (int k2 = 0; k2 < 128; k2 += 2) {
            float2 w0 = __half22float2(w1b[k2 * G_ + tid]);
            float2 w1 = __half22float2(w1b[(k2 + 1) * G_ + tid]);
            float2 a0 = xv[k2], a1 = xv[k2 + 1];
            acc0 += a0.x * w0.x + a0.y * w0.y;
            acc1 += a1.x * w1.x + a1.y * w1.y;
        }
        s_xw[tid] = bih1b[tid] + acc0 + acc1;
    }
    __syncthreads();
    if (tid < H_) {
        int j = tid;
        float rg = sigm(s_xw[j] + bhh1b[j]);
        float zg = sigm(s_xw[H_ + j] + bhh1b[H_ + j]);
        float ng = tanh_f(s_xw[2 * H_ + j] + rg * bhh1b[2 * H_ + j]);
        float hb = (1.f - zg) * ng;
        s_hc[H_ + j] = fmaxf(hb, 0.f);
        s_hc[j] = fmaxf(h1f[(size_t)b * H_ + j], 0.f);
    }
    __syncthreads();
    if (tid < HC) {
        float hv = s_hc[tid];
        float p0 = hv * fcw[tid];
        float p1 = hv * fcw[HC + tid];
#pragma unroll
        for (int off = 32; off; off >>= 1) {
            p0 += __shfl_down(p0, off);
            p1 += __shfl_down(p1, off);
        }
        if ((tid & 63) == 0) { s_red[(tid >> 6) * 2] = p0; s_red[(tid >> 6) * 2 + 1] = p1; }
    }
    __syncthreads();
    if (tid == 0) {
        out[b * 2 + 0] = fcb[0] + s_red[0] + s_red[2] + s_red[4] + s_red[6];
        out[b * 2 + 1] = fcb[1] + s_red[1] + s_red[3] + s_red[5] + s_red[7];
    }
}

extern "C" void kernel_launch(void* const* d_in, const int* in_sizes, int n_in,
                              void* d_out, int out_size, void* d_ws, size_t ws_size,
                              hipStream_t stream) {
    (void)in_sizes; (void)n_in; (void)out_size; (void)ws_size;
    const float* x     = (const float*)d_in[0];
    const float* Wih0f = (const float*)d_in[1];
    const float* Whh0f = (const float*)d_in[2];
    const float* bih0f = (const float*)d_in[3];
    const float* bhh0f = (const float*)d_in[4];
    const float* Wih0b = (const float*)d_in[5];
    const float* Whh0b = (const float*)d_in[6];
    const float* bih0b = (const float*)d_in[7];
    const float* bhh0b = (const float*)d_in[8];
    const float* Wih1f = (const float*)d_in[9];
    const float* Whh1f = (const float*)d_in[10];
    const float* bih1f = (const float*)d_in[11];
    const float* bhh1f = (const float*)d_in[12];
    const float* Wih1b = (const float*)d_in[13];
    const float* bih1b = (const float*)d_in[15];
    const float* bhh1b = (const float*)d_in[16];
    const float* fcw   = (const float*)d_in[17];
    const float* fcb   = (const float*)d_in[18];

    char* ws = (char*)d_ws;
    _Float16* out0 = (_Float16*)(ws + O_OUT0);
    _Float16* xw1  = (_Float16*)(ws + O_XW1);
    _Float16* x16  = (_Float16*)(ws + O_X16);
    __half2*  wp   = (__half2*)(ws + O_WP);
    float*    h1f  = (float*)(ws + O_H1F);
    _Float16* wf16 = (_Float16*)(ws + O_WF16);
    float*    out  = (float*)d_out;

    prep<<<4336, 256, 0, stream>>>(x, x16, Wih1f, wf16, Wih1b, wp);

    scan_l0<<<dim3(64, 2), 512, 0, stream>>>(x16, Wih0f, Whh0f, bih0f, bhh0f,
                                             Wih0b, Whh0b, bih0b, bhh0b, out0);

    gemm_xw1<<<2048, 256, 0, stream>>>(out0, wf16, bih1f, xw1);

    scan_l1<<<64, 512, 0, stream>>>(xw1, Whh1f, bhh1f, h1f);

    final_k<<<256, 384, 0, stream>>>(out0, h1f, wp, bih1b, bhh1b, fcw, fcb, out);
}